// Round 3
// baseline (6414.507 us; speedup 1.0000x reference)
//
#include <hip/hip_runtime.h>
#include <hip/hip_cooperative_groups.h>

namespace cg = cooperative_groups;

// Sizes (fixed): B=128, Tm1=64, M=P=512
typedef _Float16 v8h __attribute__((ext_vector_type(8)));
typedef _Float16 h2v __attribute__((ext_vector_type(2)));
typedef _Float16 h4v __attribute__((ext_vector_type(4)));
typedef float v4f __attribute__((ext_vector_type(4)));

__device__ __forceinline__ float fast_tanh(float x) {
    float e = __expf(2.0f * x);
    return 1.0f - 2.0f / (e + 1.0f);
}
__device__ __forceinline__ float fast_sigmoid(float x) {
    return 1.0f / (1.0f + __expf(-x));
}

// One persistent cooperative kernel: 256 blocks x 512 threads.
//  pre1: convert Xe,Wa1,Whh -> f16 ws copies; zero A=[d|c] (f16)
//  pre2: hx16 = f16(Xe @ Wa1[:,1024:]^T + ba1) via MFMA
//  loop t=0..63:
//    blocks [0,32):   s-GEMM tile (16 cols, K=1024, MFMA)    [blocks 32..160): glin
//    grid.sync()
//    blocks [192,256): pair p = bid-192: scores/softmax/context/ytilde/gates
//    grid.sync()
__global__ __launch_bounds__(512) void fused_decoder(
    const float* __restrict__ Xe, const float* __restrict__ ypr,
    const float* __restrict__ Wa1, const float* __restrict__ ba1,
    const float* __restrict__ Wa2, const float* __restrict__ ba2,
    const float* __restrict__ Wih, const float* __restrict__ Whh,
    const float* __restrict__ bih, const float* __restrict__ bhh,
    const float* __restrict__ Wfc, const float* __restrict__ bfc,
    const float* __restrict__ Wfin, const float* __restrict__ bfin,
    float* __restrict__ out,
    float* __restrict__ s, float* __restrict__ glin,
    _Float16* __restrict__ Xe16, _Float16* __restrict__ hx16,
    _Float16* __restrict__ Wa1a16, _Float16* __restrict__ Wa1x16,
    _Float16* __restrict__ Whh16, _Float16* __restrict__ Ab)
{
    cg::grid_group gg = cg::this_grid();
    const int bid = blockIdx.x;
    const int tid = threadIdx.x;
    const int wave = tid >> 6, lane = tid & 63;
    const int l15 = lane & 15, kq = lane >> 4;

    // Pair-block persistent LDS state
    __shared__ float cst[2][512];
    __shared__ float dst[2][512];
    __shared__ float ctxl[2][512];
    __shared__ float sc[128];
    __shared__ float ytl[2];
    __shared__ float red0;

    const int gt = bid * 512 + tid;   // grid-linear thread id, 131072 total

    // ---------------- pre-phase 1: f16 conversions ----------------
    {
        // Xe16: 4,194,304 f32 -> 1,048,576 float4 = 8 per thread
        const float4* Xe4 = (const float4*)Xe;
#pragma unroll
        for (int i = 0; i < 8; ++i) {
            size_t q = (size_t)gt * 8 + i;
            float4 v = Xe4[q];
            h4v h = { (_Float16)v.x, (_Float16)v.y, (_Float16)v.z, (_Float16)v.w };
            *(h4v*)(Xe16 + q * 4) = h;
        }
        // Wa1a16 [512][1024] from Wa1[e][0:1024): 131072 float4 = 1/thread
        {
            size_t q = gt;
            int row = (int)(q >> 8), c4 = (int)(q & 255);
            const float4 v = *(const float4*)(Wa1 + (size_t)row * 1536 + c4 * 4);
            h4v h = { (_Float16)v.x, (_Float16)v.y, (_Float16)v.z, (_Float16)v.w };
            *(h4v*)(Wa1a16 + (size_t)row * 1024 + c4 * 4) = h;
        }
        // Wa1x16 [512][512] from Wa1[e][1024:1536): 65536 float4 (half of threads)
        if (gt < 65536) {
            size_t q = gt;
            int row = (int)(q >> 7), c4 = (int)(q & 127);
            const float4 v = *(const float4*)(Wa1 + (size_t)row * 1536 + 1024 + c4 * 4);
            h4v h = { (_Float16)v.x, (_Float16)v.y, (_Float16)v.z, (_Float16)v.w };
            *(h4v*)(Wa1x16 + (size_t)row * 512 + c4 * 4) = h;
        }
        // Whh16 [2048][512]: 262144 float4 = 2/thread
#pragma unroll
        for (int i = 0; i < 2; ++i) {
            size_t q = (size_t)gt * 2 + i;
            const float4 v = *(const float4*)(Whh + q * 4);
            h4v h = { (_Float16)v.x, (_Float16)v.y, (_Float16)v.z, (_Float16)v.w };
            *(h4v*)(Whh16 + q * 4) = h;
        }
        // A=[d|c] zero: 131072 f16 = 1/thread
        Ab[gt] = (_Float16)0.0f;
        // pair-block LDS state zero
        for (int idx = tid; idx < 1024; idx += 512) {
            cst[idx >> 9][idx & 511] = 0.0f;
            dst[idx >> 9][idx & 511] = 0.0f;
        }
    }
    gg.sync();

    // ---------------- pre-phase 2: hx16 = f16(Xe@Wa1x^T + ba1) ----------------
    {
        // 16384 tiles (512 M x 32 N); per block 64 tiles; wave keeps M-tile fixed
        const int mt = bid * 2 + (wave >> 2);
        const _Float16* Abase = Xe16 + (size_t)(mt * 16 + l15) * 512 + kq * 8;
        v8h afr[16];
#pragma unroll
        for (int ks = 0; ks < 16; ++ks) afr[ks] = *(const v8h*)(Abase + ks * 32);
#pragma unroll
        for (int i = 0; i < 8; ++i) {
            const int nt = (wave & 3) * 8 + i;
            const _Float16* Bbase = Wa1x16 + (size_t)(nt * 16 + l15) * 512 + kq * 8;
            v4f acc = {};
#pragma unroll 4
            for (int ks = 0; ks < 16; ++ks)
                acc = __builtin_amdgcn_mfma_f32_16x16x32_f16(afr[ks], *(const v8h*)(Bbase + ks * 32), acc, 0, 0, 0);
            const float bav = ba1[nt * 16 + l15];
            _Float16* hrow = hx16 + (size_t)(mt * 16 + kq * 4) * 512 + nt * 16 + l15;
#pragma unroll
            for (int r = 0; r < 4; ++r) hrow[(size_t)r * 512] = (_Float16)(acc[r] + bav);
        }
    }
    gg.sync();

    // weight-col bias for glin blocks (static)
    float bb_g = 0.0f;
    if (bid >= 32 && bid < 160) {
        int col = (bid - 32) * 16 + l15;
        bb_g = bih[col] + bhh[col];
    }
    // pair-block static registers
    float w2v[8];
    float ba2v = 0.0f;
    const int p = bid - 192, b0 = 2 * p;
    if (bid >= 192) {
#pragma unroll
        for (int j = 0; j < 8; ++j) w2v[j] = Wa2[lane * 8 + j];
        ba2v = ba2[0];
    }

    // ---------------- main recurrence ----------------
    for (int t = 0; t < 64; ++t) {
        // ---- Phase G: s and glin GEMMs from Ab ----
        if (bid < 32) {                       // s tile: cols [16*bid, +16), K=1024
            const int col0 = bid * 16;
            const _Float16* Abase = Ab + (size_t)(wave * 16 + l15) * 1024 + kq * 8;
            const _Float16* Bbase = Wa1a16 + (size_t)(col0 + l15) * 1024 + kq * 8;
            v4f acc = {};
#pragma unroll 4
            for (int ks = 0; ks < 32; ++ks)
                acc = __builtin_amdgcn_mfma_f32_16x16x32_f16(
                    *(const v8h*)(Abase + ks * 32), *(const v8h*)(Bbase + ks * 32), acc, 0, 0, 0);
            float* srow = s + (size_t)(wave * 16 + kq * 4) * 512 + col0 + l15;
#pragma unroll
            for (int r = 0; r < 4; ++r) srow[(size_t)r * 512] = acc[r];
        } else if (bid < 160) {               // glin tile: cols [16*(bid-32), +16), K=512 (d only)
            const int col0 = (bid - 32) * 16;
            const _Float16* Abase = Ab + (size_t)(wave * 16 + l15) * 1024 + kq * 8;
            const _Float16* Bbase = Whh16 + (size_t)(col0 + l15) * 512 + kq * 8;
            v4f acc = {};
#pragma unroll 4
            for (int ks = 0; ks < 16; ++ks)
                acc = __builtin_amdgcn_mfma_f32_16x16x32_f16(
                    *(const v8h*)(Abase + ks * 32), *(const v8h*)(Bbase + ks * 32), acc, 0, 0, 0);
            float* grow = glin + (size_t)(wave * 16 + kq * 4) * 2048 + col0 + l15;
#pragma unroll
            for (int r = 0; r < 4; ++r) grow[(size_t)r * 2048] = acc[r] + bb_g;
        }
        gg.sync();

        // ---- Phase P: per batch-pair sequential chain ----
        if (bid >= 192) {
            // s rows for this pair into registers (lane owns e = lane*8..+8)
            float sreg[2][8];
#pragma unroll
            for (int blv = 0; blv < 2; ++blv) {
                const float4* sp = (const float4*)(s + (size_t)(b0 + blv) * 512 + lane * 8);
                float4 s0 = sp[0], s1 = sp[1];
                sreg[blv][0] = s0.x; sreg[blv][1] = s0.y; sreg[blv][2] = s0.z; sreg[blv][3] = s0.w;
                sreg[blv][4] = s1.x; sreg[blv][5] = s1.y; sreg[blv][6] = s1.z; sreg[blv][7] = s1.w;
            }
            // scores: 128 units (2b x 64t), 16 per wave
            for (int u0 = 0; u0 < 16; ++u0) {
                const int u = wave * 16 + u0;
                const int blv = u >> 6, tt = u & 63;
                const v8h hv = *(const v8h*)(hx16 + ((size_t)(b0 + blv) * 64 + tt) * 512 + lane * 8);
                float acc = 0.0f;
#pragma unroll
                for (int j = 0; j < 8; ++j) {
                    float x = sreg[blv][j] + (float)hv[j];
                    acc += w2v[j] * fast_tanh(x);
                }
#pragma unroll
                for (int off = 32; off; off >>= 1) acc += __shfl_xor(acc, off, 64);
                if (lane == 0) sc[u] = acc + ba2v;
            }
            __syncthreads();
            // joint softmax over the pair's 128 scores
            if (tid < 64) {
                float m2 = fmaxf(sc[tid], sc[tid + 64]);
#pragma unroll
                for (int off = 32; off; off >>= 1) m2 = fmaxf(m2, __shfl_xor(m2, off, 64));
                float e0v = __expf(sc[tid] - m2);
                float e1v = __expf(sc[tid + 64] - m2);
                sc[tid] = e0v; sc[tid + 64] = e1v;
                float ssum = e0v + e1v;
#pragma unroll
                for (int off = 32; off; off >>= 1) ssum += __shfl_xor(ssum, off, 64);
                if (tid == 0) red0 = 1.0f / ssum;
            }
            __syncthreads();
            const float inv = red0;
            // context: thread -> (bl, m-pair)
            {
                const int blv = tid >> 8, m2 = (tid & 255) * 2;
                const _Float16* xb = Xe16 + ((size_t)(b0 + blv) * 64) * 512 + m2;
                float a0 = 0.0f, a1 = 0.0f;
#pragma unroll 8
                for (int tt = 0; tt < 64; ++tt) {
                    h2v xv = *(const h2v*)(xb + (size_t)tt * 512);
                    float bta = sc[blv * 64 + tt];
                    a0 += bta * (float)xv[0];
                    a1 += bta * (float)xv[1];
                }
                ctxl[blv][m2] = a0 * inv;
                ctxl[blv][m2 + 1] = a1 * inv;
            }
            __syncthreads();
            // y_tilde
            if (tid < 128) {
                const int blv = tid >> 6, l2 = tid & 63;
                float acc = 0.0f;
#pragma unroll
                for (int j = 0; j < 8; ++j) {
                    int m = l2 * 8 + j;
                    acc += ctxl[blv][m] * Wfc[m];
                }
#pragma unroll
                for (int off = 32; off; off >>= 1) acc += __shfl_xor(acc, off, 64);
                if (l2 == 0)
                    ytl[blv] = acc + Wfc[512] * ypr[(size_t)(b0 + blv) * 64 + t] + bfc[0];
            }
            __syncthreads();
            // gates + state update; publish next A=[d|c] in f16
#pragma unroll
            for (int blv = 0; blv < 2; ++blv) {
                const int b = b0 + blv, pp = tid;
                const float* gl = glin + (size_t)b * 2048;
                const float yt = ytl[blv];
                float ii = gl[pp]         + yt * Wih[pp];
                float ff = gl[512 + pp]   + yt * Wih[512 + pp];
                float ggv = gl[1024 + pp] + yt * Wih[1024 + pp];
                float oo = gl[1536 + pp]  + yt * Wih[1536 + pp];
                float cprev = cst[blv][pp];
                float cn = fast_sigmoid(ff) * cprev + fast_sigmoid(ii) * fast_tanh(ggv);
                float dn = fast_sigmoid(oo) * fast_tanh(cn);
                cst[blv][pp] = cn;
                dst[blv][pp] = dn;
                Ab[(size_t)b * 1024 + pp]       = (_Float16)dn;
                Ab[(size_t)b * 1024 + 512 + pp] = (_Float16)cn;
            }
            if (t == 63) {
                __syncthreads();
                if (tid < 128) {
                    const int blv = tid >> 6, l2 = tid & 63;
                    float acc = 0.0f;
#pragma unroll
                    for (int j = 0; j < 8; ++j) {
                        int e = l2 * 8 + j;
                        acc += dst[blv][e] * Wfin[e] + ctxl[blv][e] * Wfin[512 + e];
                    }
#pragma unroll
                    for (int off = 32; off; off >>= 1) acc += __shfl_xor(acc, off, 64);
                    if (l2 == 0) out[b0 + blv] = acc + bfin[0];
                }
            }
        }
        gg.sync();
    }
}

extern "C" void kernel_launch(void* const* d_in, const int* in_sizes, int n_in,
                              void* d_out, int out_size, void* d_ws, size_t ws_size,
                              hipStream_t stream)
{
    const float* Xe   = (const float*)d_in[0];
    const float* ypr  = (const float*)d_in[1];
    const float* Wa1  = (const float*)d_in[2];
    const float* ba1  = (const float*)d_in[3];
    const float* Wa2  = (const float*)d_in[4];
    const float* ba2  = (const float*)d_in[5];
    const float* Wih  = (const float*)d_in[6];
    const float* Whh  = (const float*)d_in[7];
    const float* bih  = (const float*)d_in[8];
    const float* bhh  = (const float*)d_in[9];
    const float* Wfc  = (const float*)d_in[10];
    const float* bfc  = (const float*)d_in[11];
    const float* Wfin = (const float*)d_in[12];
    const float* bfin = (const float*)d_in[13];
    float* out = (float*)d_out;

    char* w = (char*)d_ws;
    float* s       = (float*)w;                     w += (size_t)128 * 512 * 4;     // 256 KB
    float* glin    = (float*)w;                     w += (size_t)128 * 2048 * 4;    // 1 MB
    _Float16* Xe16 = (_Float16*)w;                  w += (size_t)128 * 64 * 512 * 2; // 8 MB
    _Float16* hx16 = (_Float16*)w;                  w += (size_t)128 * 64 * 512 * 2; // 8 MB
    _Float16* Wa1a = (_Float16*)w;                  w += (size_t)512 * 1024 * 2;    // 1 MB
    _Float16* Wa1x = (_Float16*)w;                  w += (size_t)512 * 512 * 2;     // 0.5 MB
    _Float16* WhhH = (_Float16*)w;                  w += (size_t)2048 * 512 * 2;    // 2 MB
    _Float16* Ab   = (_Float16*)w;                  w += (size_t)128 * 1024 * 2;    // 256 KB

    void* args[] = {
        (void*)&Xe, (void*)&ypr, (void*)&Wa1, (void*)&ba1, (void*)&Wa2, (void*)&ba2,
        (void*)&Wih, (void*)&Whh, (void*)&bih, (void*)&bhh, (void*)&Wfc, (void*)&bfc,
        (void*)&Wfin, (void*)&bfin, (void*)&out,
        (void*)&s, (void*)&glin, (void*)&Xe16, (void*)&hx16,
        (void*)&Wa1a, (void*)&Wa1x, (void*)&WhhH, (void*)&Ab
    };
    hipLaunchCooperativeKernel((const void*)fused_decoder, dim3(256), dim3(512),
                               args, 0, stream);
}

// Round 6
// 3261.156 us; speedup vs baseline: 1.9669x; 1.9669x over previous
//
#include <hip/hip_runtime.h>
#include <hip/hip_cooperative_groups.h>

namespace cg = cooperative_groups;

// Problem sizes (fixed): B=128, Tm1=64, M=P=512
typedef _Float16 v8h __attribute__((ext_vector_type(8)));
typedef _Float16 h2v __attribute__((ext_vector_type(2)));
typedef float v4f __attribute__((ext_vector_type(4)));

#define SCOPE_AGENT __HIP_MEMORY_SCOPE_AGENT

static __device__ __forceinline__ uint32_t ald32(const uint32_t* p) {
    return __hip_atomic_load(p, __ATOMIC_RELAXED, SCOPE_AGENT);
}
static __device__ __forceinline__ uint64_t ald64(const uint64_t* p) {
    return __hip_atomic_load(p, __ATOMIC_RELAXED, SCOPE_AGENT);
}
static __device__ __forceinline__ void ast32(uint32_t* p, uint32_t v) {
    __hip_atomic_store(p, v, __ATOMIC_RELAXED, SCOPE_AGENT);
}
static __device__ __forceinline__ v8h mkv8(uint64_t lo, uint64_t hi) {
    union { uint64_t q[2]; v8h h; } u; u.q[0] = lo; u.q[1] = hi; return u.h;
}
static __device__ __forceinline__ uint32_t packh(float a, float b) {
    uint16_t ua = __builtin_bit_cast(uint16_t, (_Float16)a);
    uint16_t ub = __builtin_bit_cast(uint16_t, (_Float16)b);
    return (uint32_t)ua | ((uint32_t)ub << 16);
}
static __device__ __forceinline__ float fast_tanh(float x) {
    float e = __expf(2.0f * x);
    return 1.0f - 2.0f / (e + 1.0f);
}
static __device__ __forceinline__ float fast_sigmoid(float x) {
    return 1.0f / (1.0f + __expf(-x));
}
static __device__ __forceinline__ v8h cvt8(const float* p) {
    float4 a = *(const float4*)p;
    float4 b = *(const float4*)(p + 4);
    v8h h;
    h[0] = (_Float16)a.x; h[1] = (_Float16)a.y; h[2] = (_Float16)a.z; h[3] = (_Float16)a.w;
    h[4] = (_Float16)b.x; h[5] = (_Float16)b.y; h[6] = (_Float16)b.z; h[7] = (_Float16)b.w;
    return h;
}

// ---- flag barriers: agent-scope (LLC) only, no cache maintenance ----
static __device__ __forceinline__ void arrive(uint32_t* ctr) {
    asm volatile("s_waitcnt vmcnt(0)" ::: "memory");  // drain this wave's stores
    __syncthreads();                                   // all waves drained
    if (threadIdx.x == 0)
        __hip_atomic_fetch_add(ctr, 1u, __ATOMIC_RELAXED, SCOPE_AGENT);
}
static __device__ __forceinline__ void wait_ctr(uint32_t* ctr, uint32_t target) {
    if (threadIdx.x == 0) {
        while (ald32(ctr) < target) __builtin_amdgcn_s_sleep(2);
    }
    __syncthreads();
    asm volatile("" ::: "memory");
}

// Grid: 256 blocks x 512 threads, cooperative (1 block/CU).
//   bid [0,32):    s-GEMM: rows [(bid>>2)*16,+16), cols [(bid&3)*128,+128), K=1024 full chain
//   bid [32,96):   glin-GEMM: x=bid-32, rows [(x>>3)*16,+16), cols [(x&7)*256,+256), K=512 full chain
//   bid [96,192):  idle after prologue
//   bid [192,256): pair blocks (batches 2p,2p+1; coupled softmax)
__global__ __launch_bounds__(512, 2) void fused_decoder(
    const float* __restrict__ Xe, const float* __restrict__ ypr,
    const float* __restrict__ Wa1, const float* __restrict__ ba1,
    const float* __restrict__ Wa2, const float* __restrict__ ba2,
    const float* __restrict__ Wih, const float* __restrict__ Whh,
    const float* __restrict__ bih, const float* __restrict__ bhh,
    const float* __restrict__ Wfc, const float* __restrict__ bfc,
    const float* __restrict__ Wfin, const float* __restrict__ bfin,
    float* __restrict__ out,
    uint32_t* __restrict__ ctrs,          // 3 counters, 128B apart
    _Float16* __restrict__ Ab,            // [128][1024] (d|c) f16 — agent-only in main loop
    float* __restrict__ s,                // [128][512] f32 — agent-only
    float* __restrict__ glin,             // [128][2048] f32 (biases included) — agent-only
    _Float16* __restrict__ Xe16,          // [8192][512] f16 ([b*64+t][m])
    _Float16* __restrict__ hx,            // [8192][512] f16
    _Float16* __restrict__ Wa1a,          // [512][1024] f16
    _Float16* __restrict__ Whh16)         // [2048][512] f16
{
    cg::grid_group gg = cg::this_grid();
    const int bid = blockIdx.x;
    const int tid = threadIdx.x;
    const int wave = tid >> 6, lane = tid & 63;
    const int l15 = lane & 15, kq = lane >> 4;
    const int gt = bid * 512 + tid;                    // 0..131071

    uint32_t* ctrS  = ctrs + 0;
    uint32_t* ctrGL = ctrs + 32;
    uint32_t* ctrP  = ctrs + 64;

    __shared__ float s_l[2][512];
    __shared__ float gl[2][2048];
    __shared__ float sc[128];
    __shared__ float dst[2][512];
    __shared__ float cst[2][512];
    __shared__ float ctxl[2][512];
    __shared__ float ytl[2];
    __shared__ float red0;

    // ===== sync #1: flush poison-dirty ws lines from all L2s =====
    gg.sync();

    // ===== prologue: all NORMAL stores, 128B-line-owned per thread =====
    if (gt < 65536) {                      // Xe16: 65536 lines of 64 f16
        int row = gt >> 3, seg = gt & 7;
        const float* src = Xe + (size_t)row * 512 + seg * 64;
        _Float16* dp = Xe16 + (size_t)row * 512 + seg * 64;
#pragma unroll
        for (int i = 0; i < 8; ++i) *(v8h*)(dp + i * 8) = cvt8(src + i * 8);
    }
    if (gt >= 65536 && gt < 73728) {       // Wa1a [512][1024] <- Wa1[:,0:1024)
        int u = gt - 65536;
        int row = u >> 4, seg = u & 15;
        const float* src = Wa1 + (size_t)row * 1536 + seg * 64;
        _Float16* dp = Wa1a + (size_t)row * 1024 + seg * 64;
#pragma unroll
        for (int i = 0; i < 8; ++i) *(v8h*)(dp + i * 8) = cvt8(src + i * 8);
    }
    if (gt >= 73728 && gt < 90112) {       // Whh16 [2048][512]
        int u = gt - 73728;
        int row = u >> 3, seg = u & 7;
        const float* src = Whh + (size_t)row * 512 + seg * 64;
        _Float16* dp = Whh16 + (size_t)row * 512 + seg * 64;
#pragma unroll
        for (int i = 0; i < 8; ++i) *(v8h*)(dp + i * 8) = cvt8(src + i * 8);
    }
    if (gt >= 90112 && gt < 92160) {       // Ab zero: 2048 lines x 16 u64
        int u = gt - 90112;
        uint64_t* p = (uint64_t*)Ab + (size_t)u * 16;
#pragma unroll
        for (int i = 0; i < 16; ++i) p[i] = 0ull;
    }
    if (bid == 0 && tid < 3) ctrs[tid * 32] = 0u;
    for (int i = tid; i < 1024; i += 512) {            // pair LDS state
        dst[i >> 9][i & 511] = 0.0f;
        cst[i >> 9][i & 511] = 0.0f;
    }
    // hx = f16(Xe @ Wa1[:,1024:]^T + ba1), on-the-fly f32->f16 fragments
    {
        const int wg = bid * 8 + wave;                 // 0..2047
        const int mt = wg >> 2;                        // row tile 0..511
        const int nq = wg & 3;
        const float* Abase = Xe + (size_t)(mt * 16 + l15) * 512 + kq * 8;
        v8h afr[16];
#pragma unroll
        for (int ks = 0; ks < 16; ++ks) afr[ks] = cvt8(Abase + ks * 32);
#pragma unroll
        for (int i = 0; i < 8; ++i) {
            const int nt = nq * 8 + i;
            const float* Bbase = Wa1 + (size_t)(nt * 16 + l15) * 1536 + 1024 + kq * 8;
            v4f acc = {};
#pragma unroll 4
            for (int ks = 0; ks < 16; ++ks)
                acc = __builtin_amdgcn_mfma_f32_16x16x32_f16(afr[ks], cvt8(Bbase + ks * 32), acc, 0, 0, 0);
            const float bav = ba1[nt * 16 + l15];
            _Float16* hrow = hx + (size_t)(mt * 16 + kq * 4) * 512 + nt * 16 + l15;
#pragma unroll
            for (int r = 0; r < 4; ++r) hrow[(size_t)r * 512] = (_Float16)(acc[r] + bav);
        }
    }
    // ===== sync #2: publish all prologue data; all L2s clean =====
    gg.sync();

    if (bid >= 96 && bid < 192) return;    // idle blocks done

    // =========================== main recurrence =============================
    if (bid < 32) {
        // ---- s-GEMM: full K=1024 single chain (round-2 numerics) ----
        const int row16 = (bid >> 2) * 16;
        const int colw = (bid & 3) * 128 + wave * 16;
        const uint64_t* aq = (const uint64_t*)Ab + (size_t)(row16 + l15) * 256 + kq * 2;
        const _Float16* Bbase = Wa1a + (size_t)(colw + l15) * 1024 + kq * 8;
        uint32_t* op = (uint32_t*)s + (size_t)(row16 + kq * 4) * 512 + colw + l15;
        for (int t = 0; t < 64; ++t) {
            if (t) wait_ctr(ctrP, 64u * t);            // Ab(t) published
            v4f acc = {};
#pragma unroll
            for (int kk = 0; kk < 32; ++kk) {
                v8h a = mkv8(ald64(aq + kk * 8), ald64(aq + kk * 8 + 1));
                acc = __builtin_amdgcn_mfma_f32_16x16x32_f16(a, *(const v8h*)(Bbase + kk * 32), acc, 0, 0, 0);
            }
#pragma unroll
            for (int r = 0; r < 4; ++r)
                ast32(op + (size_t)r * 512, __builtin_bit_cast(uint32_t, acc[r]));
            arrive(ctrS);
        }
    } else if (bid < 96) {
        // ---- glin-GEMM: full K=512 single chain, biases at store ----
        const int x = bid - 32;
        const int row16 = (x >> 3) * 16;
        const int cg = x & 7;
        const uint64_t* aq = (const uint64_t*)Ab + (size_t)(row16 + l15) * 256 + kq * 2;
        for (int t = 0; t < 64; ++t) {
            if (t) wait_ctr(ctrP, 64u * t);
            v8h Af[16];
#pragma unroll
            for (int kk = 0; kk < 16; ++kk)
                Af[kk] = mkv8(ald64(aq + kk * 8), ald64(aq + kk * 8 + 1));
#pragma unroll
            for (int ct = 0; ct < 2; ++ct) {
                const int colw = cg * 256 + wave * 32 + ct * 16;
                const _Float16* Bbase = Whh16 + (size_t)(colw + l15) * 512 + kq * 8;
                v4f acc = {};
#pragma unroll
                for (int kk = 0; kk < 16; ++kk)
                    acc = __builtin_amdgcn_mfma_f32_16x16x32_f16(Af[kk], *(const v8h*)(Bbase + kk * 32), acc, 0, 0, 0);
                const int colo = colw + l15;
                const float bb = bih[colo] + bhh[colo];
                uint32_t* op = (uint32_t*)glin + (size_t)(row16 + kq * 4) * 2048 + colo;
#pragma unroll
                for (int r = 0; r < 4; ++r)
                    ast32(op + (size_t)r * 2048, __builtin_bit_cast(uint32_t, acc[r] + bb));
            }
            arrive(ctrGL);
        }
    } else {
        // ---- pair blocks (round-2 numerics) ----
        const int p = bid - 192, b0 = 2 * p;
        float w2v[8];
#pragma unroll
        for (int j = 0; j < 8; ++j) w2v[j] = Wa2[lane * 8 + j];
        const float ba2v = ba2[0];
        uint32_t* Abu = (uint32_t*)Ab;

        for (int t = 0; t < 64; ++t) {
            wait_ctr(ctrS, 32u * (t + 1));             // s(t) ready
            {
                int blv = tid >> 8, cp = tid & 255;    // 512 u64 items
                uint64_t q = ald64((const uint64_t*)s + (size_t)(b0 + blv) * 256 + cp);
                s_l[blv][cp * 2] = __builtin_bit_cast(float, (uint32_t)q);
                s_l[blv][cp * 2 + 1] = __builtin_bit_cast(float, (uint32_t)(q >> 32));
            }
            __syncthreads();

            // ---- scores: 128 units (2b x 64t), 16 per wave ----
            float sreg[2][8];
#pragma unroll
            for (int blv = 0; blv < 2; ++blv)
#pragma unroll
                for (int j = 0; j < 8; ++j) sreg[blv][j] = s_l[blv][lane * 8 + j];
            for (int u0 = 0; u0 < 16; ++u0) {
                const int u = wave * 16 + u0;
                const int blv = u >> 6, tt = u & 63;
                const v8h hv = *(const v8h*)(hx + ((size_t)(b0 + blv) * 64 + tt) * 512 + lane * 8);
                float acc = 0.0f;
#pragma unroll
                for (int j = 0; j < 8; ++j)
                    acc += w2v[j] * fast_tanh(sreg[blv][j] + (float)hv[j]);
#pragma unroll
                for (int off = 32; off; off >>= 1) acc += __shfl_xor(acc, off, 64);
                if (lane == 0) sc[u] = acc + ba2v;
            }
            __syncthreads();

            // ---- joint softmax over the pair's 128 scores ----
            if (tid < 64) {
                float m2 = fmaxf(sc[tid], sc[tid + 64]);
#pragma unroll
                for (int off = 32; off; off >>= 1) m2 = fmaxf(m2, __shfl_xor(m2, off, 64));
                float e0v = __expf(sc[tid] - m2);
                float e1v = __expf(sc[tid + 64] - m2);
                sc[tid] = e0v; sc[tid + 64] = e1v;
                float ssum = e0v + e1v;
#pragma unroll
                for (int off = 32; off; off >>= 1) ssum += __shfl_xor(ssum, off, 64);
                if (tid == 0) red0 = 1.0f / ssum;
            }
            __syncthreads();
            const float inv = red0;

            // ---- context from Xe16[b][t][m] (round-2 exact) ----
            {
                const int blv = tid >> 8, m2 = (tid & 255) * 2;
                const _Float16* xb = Xe16 + ((size_t)(b0 + blv) * 64) * 512 + m2;
                float a0 = 0.0f, a1 = 0.0f;
#pragma unroll 8
                for (int tt = 0; tt < 64; ++tt) {
                    h2v xv = *(const h2v*)(xb + (size_t)tt * 512);
                    float bta = sc[blv * 64 + tt];
                    a0 += bta * (float)xv[0];
                    a1 += bta * (float)xv[1];
                }
                ctxl[blv][m2] = a0 * inv;
                ctxl[blv][m2 + 1] = a1 * inv;
            }
            __syncthreads();

            // ---- y_tilde ----
            if (tid < 128) {
                const int blv = tid >> 6, l2 = tid & 63;
                float acc = 0.0f;
#pragma unroll
                for (int j = 0; j < 8; ++j) acc += ctxl[blv][l2 * 8 + j] * Wfc[l2 * 8 + j];
#pragma unroll
                for (int off = 32; off; off >>= 1) acc += __shfl_xor(acc, off, 64);
                if (l2 == 0)
                    ytl[blv] = acc + Wfc[512] * ypr[(size_t)(b0 + blv) * 64 + t] + bfc[0];
            }

            // ---- glin(t) -> LDS (also publishes ytl via its barrier) ----
            wait_ctr(ctrGL, 64u * (t + 1));
#pragma unroll
            for (int it = 0; it < 4; ++it) {           // 2048 u64 items
                int idx = tid + it * 512;
                int blv = idx >> 10, cp = idx & 1023;
                uint64_t q = ald64((const uint64_t*)glin + (size_t)(b0 + blv) * 1024 + cp);
                gl[blv][cp * 2] = __builtin_bit_cast(float, (uint32_t)q);
                gl[blv][cp * 2 + 1] = __builtin_bit_cast(float, (uint32_t)(q >> 32));
            }
            __syncthreads();

            // ---- gates + LSTM update ----
            {
                const int pp = tid;
#pragma unroll
                for (int blv = 0; blv < 2; ++blv) {
                    const float yt = ytl[blv];
                    float ii = gl[blv][pp] + yt * Wih[pp];
                    float ff = gl[blv][512 + pp] + yt * Wih[512 + pp];
                    float ggv = gl[blv][1024 + pp] + yt * Wih[1024 + pp];
                    float oo = gl[blv][1536 + pp] + yt * Wih[1536 + pp];
                    float cprev = cst[blv][pp];
                    float cn = fast_sigmoid(ff) * cprev + fast_sigmoid(ii) * fast_tanh(ggv);
                    float dn = fast_sigmoid(oo) * fast_tanh(cn);
                    cst[blv][pp] = cn;
                    dst[blv][pp] = dn;
                }
            }
            __syncthreads();
            // ---- publish Ab = [d|c] f16 (agent stores) ----
#pragma unroll
            for (int it = 0; it < 2; ++it) {
                int idx = tid + it * 512;              // 1024 u32 items
                int blv = idx >> 9, half = (idx >> 8) & 1, jj = idx & 255;
                float x0 = half ? cst[blv][jj * 2] : dst[blv][jj * 2];
                float x1 = half ? cst[blv][jj * 2 + 1] : dst[blv][jj * 2 + 1];
                ast32(Abu + (size_t)(b0 + blv) * 512 + half * 256 + jj, packh(x0, x1));
            }
            if (t == 63 && tid < 128) {
                const int blv = tid >> 6, l2 = tid & 63;
                float acc = 0.0f;
#pragma unroll
                for (int j = 0; j < 8; ++j) {
                    int e = l2 * 8 + j;
                    acc += dst[blv][e] * Wfin[e] + ctxl[blv][e] * Wfin[512 + e];
                }
#pragma unroll
                for (int off = 32; off; off >>= 1) acc += __shfl_xor(acc, off, 64);
                if (l2 == 0) out[b0 + blv] = acc + bfin[0];
            }
            arrive(ctrP);
        }
    }
}

extern "C" void kernel_launch(void* const* d_in, const int* in_sizes, int n_in,
                              void* d_out, int out_size, void* d_ws, size_t ws_size,
                              hipStream_t stream)
{
    const float* Xe   = (const float*)d_in[0];
    const float* ypr  = (const float*)d_in[1];
    const float* Wa1  = (const float*)d_in[2];
    const float* ba1  = (const float*)d_in[3];
    const float* Wa2  = (const float*)d_in[4];
    const float* ba2  = (const float*)d_in[5];
    const float* Wih  = (const float*)d_in[6];
    const float* Whh  = (const float*)d_in[7];
    const float* bih  = (const float*)d_in[8];
    const float* bhh  = (const float*)d_in[9];
    const float* Wfc  = (const float*)d_in[10];
    const float* bfc  = (const float*)d_in[11];
    const float* Wfin = (const float*)d_in[12];
    const float* bfin = (const float*)d_in[13];
    float* out = (float*)d_out;

    char* w = (char*)d_ws;
    uint32_t* ctrs  = (uint32_t*)w;                 w += 512;
    _Float16* Ab    = (_Float16*)w;                 w += (size_t)128 * 1024 * 2;      // 256 KB
    float*    s     = (float*)w;                    w += (size_t)128 * 512 * 4;       // 256 KB
    float*    glin  = (float*)w;                    w += (size_t)128 * 2048 * 4;      // 1 MB
    _Float16* Xe16  = (_Float16*)w;                 w += (size_t)8192 * 512 * 2;      // 8 MB
    _Float16* hx    = (_Float16*)w;                 w += (size_t)8192 * 512 * 2;      // 8 MB
    _Float16* Wa1a  = (_Float16*)w;                 w += (size_t)512 * 1024 * 2;      // 1 MB
    _Float16* Whh16 = (_Float16*)w;                 w += (size_t)2048 * 512 * 2;      // 2 MB

    void* args[] = {
        (void*)&Xe, (void*)&ypr, (void*)&Wa1, (void*)&ba1, (void*)&Wa2, (void*)&ba2,
        (void*)&Wih, (void*)&Whh, (void*)&bih, (void*)&bhh, (void*)&Wfc, (void*)&bfc,
        (void*)&Wfin, (void*)&bfin, (void*)&out,
        (void*)&ctrs, (void*)&Ab, (void*)&s, (void*)&glin, (void*)&Xe16, (void*)&hx,
        (void*)&Wa1a, (void*)&Whh16
    };
    hipLaunchCooperativeKernel((const void*)fused_decoder, dim3(256), dim3(512),
                               args, 0, stream);
}

// Round 7
// 2279.917 us; speedup vs baseline: 2.8135x; 1.4304x over previous
//
#include <hip/hip_runtime.h>
#include <hip/hip_cooperative_groups.h>

namespace cg = cooperative_groups;

// Problem sizes (fixed): B=128, Tm1=64, M=P=512
typedef _Float16 v8h __attribute__((ext_vector_type(8)));
typedef _Float16 h2v __attribute__((ext_vector_type(2)));
typedef _Float16 h4v __attribute__((ext_vector_type(4)));
typedef float v4f __attribute__((ext_vector_type(4)));

#define SCOPE_AGENT __HIP_MEMORY_SCOPE_AGENT

static __device__ __forceinline__ uint32_t ald32(const uint32_t* p) {
    return __hip_atomic_load(p, __ATOMIC_RELAXED, SCOPE_AGENT);
}
static __device__ __forceinline__ uint64_t ald64(const uint64_t* p) {
    return __hip_atomic_load(p, __ATOMIC_RELAXED, SCOPE_AGENT);
}
static __device__ __forceinline__ void ast32(uint32_t* p, uint32_t v) {
    __hip_atomic_store(p, v, __ATOMIC_RELAXED, SCOPE_AGENT);
}
static __device__ __forceinline__ v8h mkv8(uint64_t lo, uint64_t hi) {
    union { uint64_t q[2]; v8h h; } u; u.q[0] = lo; u.q[1] = hi; return u.h;
}
static __device__ __forceinline__ uint32_t packh(float a, float b) {
    uint16_t ua = __builtin_bit_cast(uint16_t, (_Float16)a);
    uint16_t ub = __builtin_bit_cast(uint16_t, (_Float16)b);
    return (uint32_t)ua | ((uint32_t)ub << 16);
}
static __device__ __forceinline__ float fast_tanh(float x) {
    float e = __expf(2.0f * x);
    return 1.0f - 2.0f / (e + 1.0f);
}
static __device__ __forceinline__ float fast_sigmoid(float x) {
    return 1.0f / (1.0f + __expf(-x));
}
static __device__ __forceinline__ v8h cvt8(const float* p) {
    float4 a = *(const float4*)p;
    float4 b = *(const float4*)(p + 4);
    v8h h;
    h[0] = (_Float16)a.x; h[1] = (_Float16)a.y; h[2] = (_Float16)a.z; h[3] = (_Float16)a.w;
    h[4] = (_Float16)b.x; h[5] = (_Float16)b.y; h[6] = (_Float16)b.z; h[7] = (_Float16)b.w;
    return h;
}

// ---- flag barriers: agent-scope (LLC) only, no cache maintenance ----
static __device__ __forceinline__ void arrive(uint32_t* ctr) {
    asm volatile("s_waitcnt vmcnt(0)" ::: "memory");  // drain this wave's stores
    __syncthreads();                                   // all waves drained
    if (threadIdx.x == 0)
        __hip_atomic_fetch_add(ctr, 1u, __ATOMIC_RELAXED, SCOPE_AGENT);
}
static __device__ __forceinline__ void wait_ctr(uint32_t* ctr, uint32_t target) {
    if (threadIdx.x == 0) {
        while (ald32(ctr) < target) __builtin_amdgcn_s_sleep(1);
    }
    __syncthreads();
    asm volatile("" ::: "memory");
}

// Grid: 256 blocks x 512 threads, cooperative (1 block/CU).
// 8 groups, group r = batches [16r, 16r+16):
//   s-blocks    bid 0..31:   r=bid>>2,    c=bid&3   (cols 128c..+128, K=1024)
//   glin-blocks bid 32..95:  r=(bid-32)>>3, c=(bid-32)&7 (cols 256c..+256, K=512)
//   idle        bid 96..191
//   pair-blocks bid 192..255: p=bid-192, r=p>>3 (batches 2p, 2p+1)
// Flags (128B-separated lines): ctrS[r]=ctrs[r*32], ctrGL[r]=ctrs[256+r*32],
//                               ctrP[r]=ctrs[512+r*32]
__global__ __launch_bounds__(512, 2) void fused_decoder(
    const float* __restrict__ Xe, const float* __restrict__ ypr,
    const float* __restrict__ Wa1, const float* __restrict__ ba1,
    const float* __restrict__ Wa2, const float* __restrict__ ba2,
    const float* __restrict__ Wih, const float* __restrict__ Whh,
    const float* __restrict__ bih, const float* __restrict__ bhh,
    const float* __restrict__ Wfc, const float* __restrict__ bfc,
    const float* __restrict__ Wfin, const float* __restrict__ bfin,
    float* __restrict__ out,
    uint32_t* __restrict__ ctrs,          // 768 u32 (3 x 8 lines)
    _Float16* __restrict__ Ab,            // [128][1024] (d|c) f16 — agent-only
    float* __restrict__ s,                // [128][512] f32 — agent-only
    float* __restrict__ glin,             // [128][2048] f32 (+biases) — agent-only
    _Float16* __restrict__ Xe16,          // [8192][512] f16 ([b*64+t][m])
    _Float16* __restrict__ hx,            // [8192][512] f16
    _Float16* __restrict__ Wa1a,          // [512][1024] f16
    _Float16* __restrict__ Whh16)         // [2048][512] f16
{
    cg::grid_group gg = cg::this_grid();
    const int bid = blockIdx.x;
    const int tid = threadIdx.x;
    const int wave = tid >> 6, lane = tid & 63;
    const int l15 = lane & 15, kq = lane >> 4;
    const int gt = bid * 512 + tid;                    // 0..131071

    // A-tile staging, k-major: frag(row,kq,kk) at f16 idx kk*512 + kq*128 + row*8
    __shared__ _Float16 Atile[16384];                  // 32 KB (GEMM blocks)
    // pair-block LDS
    __shared__ float s_l[2][512];
    __shared__ float sc[128];
    __shared__ float dstL[2][512];
    __shared__ float cstL[2][512];
    __shared__ float ctxl[2][512];
    __shared__ float ytl[2];
    __shared__ float red0;

    // ===== sync #1: flush poison-dirty ws lines from all L2s =====
    gg.sync();

    // ===== prologue: all NORMAL stores, 128B-line-owned per thread =====
    if (gt < 65536) {                      // Xe16: 65536 lines of 64 f16
        int row = gt >> 3, seg = gt & 7;
        const float* src = Xe + (size_t)row * 512 + seg * 64;
        _Float16* dp = Xe16 + (size_t)row * 512 + seg * 64;
#pragma unroll
        for (int i = 0; i < 8; ++i) *(v8h*)(dp + i * 8) = cvt8(src + i * 8);
    }
    if (gt >= 65536 && gt < 73728) {       // Wa1a [512][1024] <- Wa1[:,0:1024)
        int u = gt - 65536;
        int row = u >> 4, seg = u & 15;
        const float* src = Wa1 + (size_t)row * 1536 + seg * 64;
        _Float16* dp = Wa1a + (size_t)row * 1024 + seg * 64;
#pragma unroll
        for (int i = 0; i < 8; ++i) *(v8h*)(dp + i * 8) = cvt8(src + i * 8);
    }
    if (gt >= 73728 && gt < 90112) {       // Whh16 [2048][512]
        int u = gt - 73728;
        int row = u >> 3, seg = u & 7;
        const float* src = Whh + (size_t)row * 512 + seg * 64;
        _Float16* dp = Whh16 + (size_t)row * 512 + seg * 64;
#pragma unroll
        for (int i = 0; i < 8; ++i) *(v8h*)(dp + i * 8) = cvt8(src + i * 8);
    }
    if (gt >= 90112 && gt < 92160) {       // Ab zero: 2048 lines x 16 u64
        int u = gt - 90112;
        uint64_t* p = (uint64_t*)Ab + (size_t)u * 16;
#pragma unroll
        for (int i = 0; i < 16; ++i) p[i] = 0ull;
    }
    if (bid == 0) {                        // flags zero (768 u32)
        for (int i = tid; i < 768; i += 512) ctrs[i] = 0u;
    }
    for (int i = tid; i < 1024; i += 512) {            // pair LDS state
        dstL[i >> 9][i & 511] = 0.0f;
        cstL[i >> 9][i & 511] = 0.0f;
    }
    // hx = f16(Xe @ Wa1[:,1024:]^T + ba1), on-the-fly f32->f16 fragments
    {
        const int wg = bid * 8 + wave;                 // 0..2047
        const int mt = wg >> 2;                        // row tile 0..511
        const int nq = wg & 3;
        const float* Abase = Xe + (size_t)(mt * 16 + l15) * 512 + kq * 8;
        v8h afr[16];
#pragma unroll
        for (int ks = 0; ks < 16; ++ks) afr[ks] = cvt8(Abase + ks * 32);
#pragma unroll
        for (int i = 0; i < 8; ++i) {
            const int nt = nq * 8 + i;
            const float* Bbase = Wa1 + (size_t)(nt * 16 + l15) * 1536 + 1024 + kq * 8;
            v4f acc = {};
#pragma unroll 4
            for (int ks = 0; ks < 16; ++ks)
                acc = __builtin_amdgcn_mfma_f32_16x16x32_f16(afr[ks], cvt8(Bbase + ks * 32), acc, 0, 0, 0);
            const float bav = ba1[nt * 16 + l15];
            _Float16* hrow = hx + (size_t)(mt * 16 + kq * 4) * 512 + nt * 16 + l15;
#pragma unroll
            for (int r = 0; r < 4; ++r) hrow[(size_t)r * 512] = (_Float16)(acc[r] + bav);
        }
    }
    // ===== sync #2: publish all prologue data; all L2s clean =====
    gg.sync();

    if (bid >= 96 && bid < 192) return;    // idle blocks done

    // =========================== main recurrence =============================
    if (bid < 32) {
        // ---- s-GEMM: rows 16r..+16, cols 128c..+128, K=1024 full chain ----
        const int r = bid >> 2, cblk = bid & 3;
        const int g16 = r * 16;
        const int colw = cblk * 128 + wave * 16;
        uint32_t* myS = ctrs + r * 32;
        uint32_t* myP = ctrs + 512 + r * 32;
        const int srow = tid & 15, sseg = tid >> 4;    // staging assignment (32 segs)
        const uint64_t* asrc = (const uint64_t*)Ab + (size_t)(g16 + srow) * 256 + sseg * 8;
        const _Float16* Bbase = Wa1a + (size_t)(colw + l15) * 1024 + kq * 8;
        uint32_t* op = (uint32_t*)s + (size_t)(g16 + kq * 4) * 512 + colw + l15;

        for (int t = 0; t < 64; ++t) {
            if (t) wait_ctr(myP, 8u * t);              // Ab(t) published by 8 pairs
            // stage A-tile (32 KB) cooperatively, one parallel LLC burst
            uint64_t v[8];
#pragma unroll
            for (int i = 0; i < 8; ++i) v[i] = ald64(asrc + i);
#pragma unroll
            for (int q = 0; q < 4; ++q)
                *(v8h*)(Atile + sseg * 512 + q * 128 + srow * 8) = mkv8(v[2 * q], v[2 * q + 1]);
            __syncthreads();
            v4f acc = {};
#pragma unroll
            for (int kk = 0; kk < 32; ++kk)
                acc = __builtin_amdgcn_mfma_f32_16x16x32_f16(
                    *(const v8h*)(Atile + kk * 512 + kq * 128 + l15 * 8),
                    *(const v8h*)(Bbase + kk * 32), acc, 0, 0, 0);
#pragma unroll
            for (int rr = 0; rr < 4; ++rr)
                ast32(op + (size_t)rr * 512, __builtin_bit_cast(uint32_t, acc[rr]));
            arrive(myS);
        }
    } else if (bid < 96) {
        // ---- glin-GEMM: rows 16r..+16, cols 256c..+256, K=512 full chain ----
        const int x = bid - 32;
        const int r = x >> 3, cblk = x & 7;
        const int g16 = r * 16;
        uint32_t* myGL = ctrs + 256 + r * 32;
        uint32_t* myP = ctrs + 512 + r * 32;
        const int srow = tid & 15, sseg = tid >> 4;    // only tid<256 stage (16 segs)
        const uint64_t* asrc = (const uint64_t*)Ab + (size_t)(g16 + srow) * 256 + sseg * 8;
        float bb[2];
        const _Float16* Bb[2];
        uint32_t* op[2];
#pragma unroll
        for (int ct = 0; ct < 2; ++ct) {
            const int colo = cblk * 256 + wave * 32 + ct * 16 + l15;
            bb[ct] = bih[colo] + bhh[colo];
            Bb[ct] = Whh16 + (size_t)colo * 512 + kq * 8;
            op[ct] = (uint32_t*)glin + (size_t)(g16 + kq * 4) * 2048 + colo;
        }

        for (int t = 0; t < 64; ++t) {
            if (t) wait_ctr(myP, 8u * t);
            if (tid < 256) {               // stage d-half (16 KB)
                uint64_t v[8];
#pragma unroll
                for (int i = 0; i < 8; ++i) v[i] = ald64(asrc + i);
#pragma unroll
                for (int q = 0; q < 4; ++q)
                    *(v8h*)(Atile + sseg * 512 + q * 128 + srow * 8) = mkv8(v[2 * q], v[2 * q + 1]);
            }
            __syncthreads();
#pragma unroll
            for (int ct = 0; ct < 2; ++ct) {
                v4f acc = {};
#pragma unroll
                for (int kk = 0; kk < 16; ++kk)
                    acc = __builtin_amdgcn_mfma_f32_16x16x32_f16(
                        *(const v8h*)(Atile + kk * 512 + kq * 128 + l15 * 8),
                        *(const v8h*)(Bb[ct] + kk * 32), acc, 0, 0, 0);
#pragma unroll
                for (int rr = 0; rr < 4; ++rr)
                    ast32(op[ct] + (size_t)rr * 2048,
                          __builtin_bit_cast(uint32_t, acc[rr] + bb[ct]));
            }
            arrive(myGL);
        }
    } else {
        // ---- pair blocks ----
        const int p = bid - 192, b0 = 2 * p, r = p >> 3;
        uint32_t* wS = ctrs + r * 32;
        uint32_t* wGL = ctrs + 256 + r * 32;
        uint32_t* aP = ctrs + 512 + r * 32;
        float w2v[8];
#pragma unroll
        for (int j = 0; j < 8; ++j) w2v[j] = Wa2[lane * 8 + j];
        const float ba2v = ba2[0];
        const float wih_i = Wih[tid], wih_f = Wih[512 + tid],
                    wih_g = Wih[1024 + tid], wih_o = Wih[1536 + tid];
        uint32_t* Abu = (uint32_t*)Ab;

        for (int t = 0; t < 64; ++t) {
            wait_ctr(wS, 4u * (t + 1));                // s(t) ready (4 s-blocks)
            {
                int blv = tid >> 8, cp = tid & 255;    // 512 u64 items
                uint64_t q = ald64((const uint64_t*)s + (size_t)(b0 + blv) * 256 + cp);
                s_l[blv][cp * 2] = __builtin_bit_cast(float, (uint32_t)q);
                s_l[blv][cp * 2 + 1] = __builtin_bit_cast(float, (uint32_t)(q >> 32));
            }
            __syncthreads();

            // ---- scores: 128 units (2b x 64t), 16 per wave ----
            float sreg[2][8];
#pragma unroll
            for (int blv = 0; blv < 2; ++blv)
#pragma unroll
                for (int j = 0; j < 8; ++j) sreg[blv][j] = s_l[blv][lane * 8 + j];
            for (int u0 = 0; u0 < 16; ++u0) {
                const int u = wave * 16 + u0;
                const int blv = u >> 6, tt = u & 63;
                const v8h hv = *(const v8h*)(hx + ((size_t)(b0 + blv) * 64 + tt) * 512 + lane * 8);
                float acc = 0.0f;
#pragma unroll
                for (int j = 0; j < 8; ++j)
                    acc += w2v[j] * fast_tanh(sreg[blv][j] + (float)hv[j]);
#pragma unroll
                for (int off = 32; off; off >>= 1) acc += __shfl_xor(acc, off, 64);
                if (lane == 0) sc[u] = acc + ba2v;
            }
            __syncthreads();

            // ---- joint softmax over the pair's 128 scores ----
            if (tid < 64) {
                float m2 = fmaxf(sc[tid], sc[tid + 64]);
#pragma unroll
                for (int off = 32; off; off >>= 1) m2 = fmaxf(m2, __shfl_xor(m2, off, 64));
                float e0v = __expf(sc[tid] - m2);
                float e1v = __expf(sc[tid + 64] - m2);
                sc[tid] = e0v; sc[tid + 64] = e1v;
                float ssum = e0v + e1v;
#pragma unroll
                for (int off = 32; off; off >>= 1) ssum += __shfl_xor(ssum, off, 64);
                if (tid == 0) red0 = 1.0f / ssum;
            }
            __syncthreads();
            const float inv = red0;

            // ---- context from Xe16[b][t][m], non-temporal stream ----
            {
                const int blv = tid >> 8, m2 = (tid & 255) * 2;
                const uint32_t* xb = (const uint32_t*)(Xe16 + ((size_t)(b0 + blv) * 64) * 512 + m2);
                float a0 = 0.0f, a1 = 0.0f;
#pragma unroll 8
                for (int tt = 0; tt < 64; ++tt) {
                    uint32_t raw = __builtin_nontemporal_load(xb + (size_t)tt * 256);
                    h2v xv = __builtin_bit_cast(h2v, raw);
                    float bta = sc[blv * 64 + tt];
                    a0 += bta * (float)xv[0];
                    a1 += bta * (float)xv[1];
                }
                ctxl[blv][m2] = a0 * inv;
                ctxl[blv][m2 + 1] = a1 * inv;
            }
            __syncthreads();

            // ---- y_tilde ----
            if (tid < 128) {
                const int blv = tid >> 6, l2 = tid & 63;
                float acc = 0.0f;
#pragma unroll
                for (int j = 0; j < 8; ++j) acc += ctxl[blv][l2 * 8 + j] * Wfc[l2 * 8 + j];
#pragma unroll
                for (int off = 32; off; off >>= 1) acc += __shfl_xor(acc, off, 64);
                if (l2 == 0)
                    ytl[blv] = acc + Wfc[512] * ypr[(size_t)(b0 + blv) * 64 + t] + bfc[0];
            }

            // ---- glin(t) direct + gates + LSTM update ----
            wait_ctr(wGL, 8u * (t + 1));               // also publishes ytl
            {
                const int pp = tid;
#pragma unroll
                for (int blv = 0; blv < 2; ++blv) {
                    const uint32_t* gb = (const uint32_t*)glin + (size_t)(b0 + blv) * 2048 + pp;
                    const float yt = ytl[blv];
                    float ii = __builtin_bit_cast(float, ald32(gb)) + yt * wih_i;
                    float ff = __builtin_bit_cast(float, ald32(gb + 512)) + yt * wih_f;
                    float ggv = __builtin_bit_cast(float, ald32(gb + 1024)) + yt * wih_g;
                    float oo = __builtin_bit_cast(float, ald32(gb + 1536)) + yt * wih_o;
                    float cprev = cstL[blv][pp];
                    float cn = fast_sigmoid(ff) * cprev + fast_sigmoid(ii) * fast_tanh(ggv);
                    float dn = fast_sigmoid(oo) * fast_tanh(cn);
                    cstL[blv][pp] = cn;
                    dstL[blv][pp] = dn;
                }
            }
            __syncthreads();
            // ---- publish Ab = [d|c] f16 (agent stores) ----
#pragma unroll
            for (int it = 0; it < 2; ++it) {
                int idx = tid + it * 512;              // 1024 u32 items
                int blv = idx >> 9, half = (idx >> 8) & 1, jj = idx & 255;
                float x0 = half ? cstL[blv][jj * 2] : dstL[blv][jj * 2];
                float x1 = half ? cstL[blv][jj * 2 + 1] : dstL[blv][jj * 2 + 1];
                ast32(Abu + (size_t)(b0 + blv) * 512 + half * 256 + jj, packh(x0, x1));
            }
            if (t == 63 && tid < 128) {
                const int blv = tid >> 6, l2 = tid & 63;
                float acc = 0.0f;
#pragma unroll
                for (int j = 0; j < 8; ++j) {
                    int e = l2 * 8 + j;
                    acc += dstL[blv][e] * Wfin[e] + ctxl[blv][e] * Wfin[512 + e];
                }
#pragma unroll
                for (int off = 32; off; off >>= 1) acc += __shfl_xor(acc, off, 64);
                if (l2 == 0) out[b0 + blv] = acc + bfin[0];
            }
            arrive(aP);
        }
    }
}

extern "C" void kernel_launch(void* const* d_in, const int* in_sizes, int n_in,
                              void* d_out, int out_size, void* d_ws, size_t ws_size,
                              hipStream_t stream)
{
    const float* Xe   = (const float*)d_in[0];
    const float* ypr  = (const float*)d_in[1];
    const float* Wa1  = (const float*)d_in[2];
    const float* ba1  = (const float*)d_in[3];
    const float* Wa2  = (const float*)d_in[4];
    const float* ba2  = (const float*)d_in[5];
    const float* Wih  = (const float*)d_in[6];
    const float* Whh  = (const float*)d_in[7];
    const float* bih  = (const float*)d_in[8];
    const float* bhh  = (const float*)d_in[9];
    const float* Wfc  = (const float*)d_in[10];
    const float* bfc  = (const float*)d_in[11];
    const float* Wfin = (const float*)d_in[12];
    const float* bfin = (const float*)d_in[13];
    float* out = (float*)d_out;

    char* w = (char*)d_ws;
    uint32_t* ctrs  = (uint32_t*)w;                 w += 4096;
    _Float16* Ab    = (_Float16*)w;                 w += (size_t)128 * 1024 * 2;      // 256 KB
    float*    s     = (float*)w;                    w += (size_t)128 * 512 * 4;       // 256 KB
    float*    glin  = (float*)w;                    w += (size_t)128 * 2048 * 4;      // 1 MB
    _Float16* Xe16  = (_Float16*)w;                 w += (size_t)8192 * 512 * 2;      // 8 MB
    _Float16* hx    = (_Float16*)w;                 w += (size_t)8192 * 512 * 2;      // 8 MB
    _Float16* Wa1a  = (_Float16*)w;                 w += (size_t)512 * 1024 * 2;      // 1 MB
    _Float16* Whh16 = (_Float16*)w;                 w += (size_t)2048 * 512 * 2;      // 2 MB

    void* args[] = {
        (void*)&Xe, (void*)&ypr, (void*)&Wa1, (void*)&ba1, (void*)&Wa2, (void*)&ba2,
        (void*)&Wih, (void*)&Whh, (void*)&bih, (void*)&bhh, (void*)&Wfc, (void*)&bfc,
        (void*)&Wfin, (void*)&bfin, (void*)&out,
        (void*)&ctrs, (void*)&Ab, (void*)&s, (void*)&glin, (void*)&Xe16, (void*)&hx,
        (void*)&Wa1a, (void*)&Whh16
    };
    hipLaunchCooperativeKernel((const void*)fused_decoder, dim3(256), dim3(512),
                               args, 0, stream);
}

// Round 8
// 1347.894 us; speedup vs baseline: 4.7589x; 1.6915x over previous
//
#include <hip/hip_runtime.h>
#include <hip/hip_cooperative_groups.h>

namespace cg = cooperative_groups;

// Problem sizes (fixed): B=128, Tm1=64, M=P=512
typedef _Float16 v8h __attribute__((ext_vector_type(8)));
typedef _Float16 h2v __attribute__((ext_vector_type(2)));
typedef _Float16 h4v __attribute__((ext_vector_type(4)));
typedef float v4f __attribute__((ext_vector_type(4)));

#define SCOPE_AGENT __HIP_MEMORY_SCOPE_AGENT

static __device__ __forceinline__ uint32_t ald32(const uint32_t* p) {
    return __hip_atomic_load(p, __ATOMIC_RELAXED, SCOPE_AGENT);
}
static __device__ __forceinline__ uint64_t ald64(const uint64_t* p) {
    return __hip_atomic_load(p, __ATOMIC_RELAXED, SCOPE_AGENT);
}
static __device__ __forceinline__ void ast32(uint32_t* p, uint32_t v) {
    __hip_atomic_store(p, v, __ATOMIC_RELAXED, SCOPE_AGENT);
}
static __device__ __forceinline__ v8h mkv8(uint64_t lo, uint64_t hi) {
    union { uint64_t q[2]; v8h h; } u; u.q[0] = lo; u.q[1] = hi; return u.h;
}
static __device__ __forceinline__ uint32_t packh(float a, float b) {
    uint16_t ua = __builtin_bit_cast(uint16_t, (_Float16)a);
    uint16_t ub = __builtin_bit_cast(uint16_t, (_Float16)b);
    return (uint32_t)ua | ((uint32_t)ub << 16);
}
static __device__ __forceinline__ float fast_tanh(float x) {
    float e = __expf(2.0f * x);
    return 1.0f - 2.0f / (e + 1.0f);
}
static __device__ __forceinline__ float fast_sigmoid(float x) {
    return 1.0f / (1.0f + __expf(-x));
}
static __device__ __forceinline__ v8h cvt8(const float* p) {
    float4 a = *(const float4*)p;
    float4 b = *(const float4*)(p + 4);
    v8h h;
    h[0] = (_Float16)a.x; h[1] = (_Float16)a.y; h[2] = (_Float16)a.z; h[3] = (_Float16)a.w;
    h[4] = (_Float16)b.x; h[5] = (_Float16)b.y; h[6] = (_Float16)b.z; h[7] = (_Float16)b.w;
    return h;
}

// ---- single-writer flag lines (128 B apart); wave-parallel polling ----
static __device__ __forceinline__ void set_flag(uint32_t* line, uint32_t v) {
    asm volatile("s_waitcnt vmcnt(0)" ::: "memory");  // drain this wave's stores
    __syncthreads();                                   // all waves drained
    if (threadIdx.x == 0) ast32(line, v);
}
// poll n (power of 2, <=64) lines in parallel with wave 0's lanes
static __device__ __forceinline__ void wait_flags(const uint32_t* base, int n, uint32_t target) {
    if (threadIdx.x < 64) {
        const uint32_t* p = base + (threadIdx.x & (n - 1)) * 32;
        while (ald32(p) < target) __builtin_amdgcn_s_sleep(1);
    }
    __syncthreads();
    asm volatile("" ::: "memory");
}

// Grid: 256 blocks x 512 threads, cooperative (1 block/CU).
// 8 groups, group r = batches [16r, 16r+16):
//   worker blocks bid 0..127: r=bid>>4, w=bid&15
//     s-slice: cols [32w,+32) K=1024 (K-split over 8 waves + LDS reduce)
//     + tanh score partials over e-slice [32w,+32)
//     + glin-slice: cols [128w,+128) K=512 (1 n-tile per wave)
//   idle bid 128..191 (after prologue)
//   pair blocks bid 192..255: p=bid-192, r=p>>3 (batches 2p,2p+1)
// Flags: flagP[p]   at ctrs + p*32            (pair p finished step -> t+1)
//        flagWA[wi] at ctrs + (64+wi)*32      (worker wi score-partials ready)
//        flagWB[wi] at ctrs + (192+wi)*32     (worker wi glin ready)
__global__ __launch_bounds__(512, 2) void fused_decoder(
    const float* __restrict__ Xe, const float* __restrict__ ypr,
    const float* __restrict__ Wa1, const float* __restrict__ ba1,
    const float* __restrict__ Wa2, const float* __restrict__ ba2,
    const float* __restrict__ Wih, const float* __restrict__ Whh,
    const float* __restrict__ bih, const float* __restrict__ bhh,
    const float* __restrict__ Wfc, const float* __restrict__ bfc,
    const float* __restrict__ Wfin, const float* __restrict__ bfin,
    float* __restrict__ out,
    uint32_t* __restrict__ ctrs,          // 320 flag lines (40 KB)
    _Float16* __restrict__ Ab,            // [128][1024] (d|c) f16 — agent-only
    float* __restrict__ glin,             // [128][2048] f32 (+biases) — agent-only
    float* __restrict__ partS,            // [128 workers][16 b][64 t] f32 — agent-only
    _Float16* __restrict__ Xe16,          // [8192][512] f16 ([b*64+t][m])
    _Float16* __restrict__ hx,            // [8192][512] f16
    _Float16* __restrict__ Wa1a,          // [512][1024] f16
    _Float16* __restrict__ Whh16)         // [2048][512] f16
{
    cg::grid_group gg = cg::this_grid();
    const int bid = blockIdx.x;
    const int tid = threadIdx.x;
    const int wave = tid >> 6, lane = tid & 63;
    const int l15 = lane & 15, kq = lane >> 4;
    const int gt = bid * 512 + tid;                    // 0..131071

    // worker LDS
    __shared__ _Float16 Atile[16384];                  // 32 KB staged A ([kseg][kq][row][8])
    __shared__ float sRed[8 * 512];                    // 16 KB K-split partials
    __shared__ float s_tile[512];                      // [b][e-slice 32]
    __shared__ float w2l[32];
    // pair LDS
    __shared__ float sc[128];
    __shared__ float dstL[2][512];
    __shared__ float cstL[2][512];
    __shared__ float ctxl[2][512];
    __shared__ float ytl[2];
    __shared__ float red0;

    // ===== sync #1: flush poison-dirty ws lines from all L2s =====
    gg.sync();

    // ===== prologue: all NORMAL stores, 128B-line-owned per thread =====
    if (gt < 65536) {                      // Xe16: 65536 lines of 64 f16
        int row = gt >> 3, seg = gt & 7;
        const float* src = Xe + (size_t)row * 512 + seg * 64;
        _Float16* dp = Xe16 + (size_t)row * 512 + seg * 64;
#pragma unroll
        for (int i = 0; i < 8; ++i) *(v8h*)(dp + i * 8) = cvt8(src + i * 8);
    }
    if (gt >= 65536 && gt < 73728) {       // Wa1a [512][1024] <- Wa1[:,0:1024)
        int u = gt - 65536;
        int row = u >> 4, seg = u & 15;
        const float* src = Wa1 + (size_t)row * 1536 + seg * 64;
        _Float16* dp = Wa1a + (size_t)row * 1024 + seg * 64;
#pragma unroll
        for (int i = 0; i < 8; ++i) *(v8h*)(dp + i * 8) = cvt8(src + i * 8);
    }
    if (gt >= 73728 && gt < 90112) {       // Whh16 [2048][512]
        int u = gt - 73728;
        int row = u >> 3, seg = u & 7;
        const float* src = Whh + (size_t)row * 512 + seg * 64;
        _Float16* dp = Whh16 + (size_t)row * 512 + seg * 64;
#pragma unroll
        for (int i = 0; i < 8; ++i) *(v8h*)(dp + i * 8) = cvt8(src + i * 8);
    }
    if (gt >= 90112 && gt < 92160) {       // Ab zero: 2048 lines x 16 u64
        int u = gt - 90112;
        uint64_t* p = (uint64_t*)Ab + (size_t)u * 16;
#pragma unroll
        for (int i = 0; i < 16; ++i) p[i] = 0ull;
    }
    if (gt >= 92160 && gt < 102400) {      // flags zero: 10240 u32 (40 KB)
        ctrs[gt - 92160] = 0u;
    }
    for (int i = tid; i < 1024; i += 512) {            // pair LDS state
        dstL[i >> 9][i & 511] = 0.0f;
        cstL[i >> 9][i & 511] = 0.0f;
    }
    // hx = f16(Xe @ Wa1[:,1024:]^T + ba1), on-the-fly f32->f16 fragments
    {
        const int wg = bid * 8 + wave;                 // 0..2047
        const int mt = wg >> 2;                        // row tile 0..511
        const int nq = wg & 3;
        const float* Abase = Xe + (size_t)(mt * 16 + l15) * 512 + kq * 8;
        v8h afr[16];
#pragma unroll
        for (int ks = 0; ks < 16; ++ks) afr[ks] = cvt8(Abase + ks * 32);
#pragma unroll
        for (int i = 0; i < 8; ++i) {
            const int nt = nq * 8 + i;
            const float* Bbase = Wa1 + (size_t)(nt * 16 + l15) * 1536 + 1024 + kq * 8;
            v4f acc = {};
#pragma unroll 4
            for (int ks = 0; ks < 16; ++ks)
                acc = __builtin_amdgcn_mfma_f32_16x16x32_f16(afr[ks], cvt8(Bbase + ks * 32), acc, 0, 0, 0);
            const float bav = ba1[nt * 16 + l15];
            _Float16* hrow = hx + (size_t)(mt * 16 + kq * 4) * 512 + nt * 16 + l15;
#pragma unroll
            for (int r = 0; r < 4; ++r) hrow[(size_t)r * 512] = (_Float16)(acc[r] + bav);
        }
    }
    // ===== sync #2: publish all prologue data; all L2s clean =====
    gg.sync();

    if (bid >= 128 && bid < 192) return;   // idle blocks done

    // =========================== main recurrence =============================
    if (bid < 128) {
        // ------------------ worker blocks ------------------
        const int r = bid >> 4, w = bid & 15;
        const int g16 = r * 16;
        uint32_t* fWA = ctrs + (64 + bid) * 32;
        uint32_t* fWB = ctrs + (192 + bid) * 32;
        const uint32_t* fP = ctrs + (r * 8) * 32;

        if (tid < 32) w2l[tid] = Wa2[w * 32 + tid];

        const int srow = tid & 15, sseg = tid >> 4;    // staging: 16 rows x 32 ksegs
        const uint64_t* asrc = (const uint64_t*)Ab + (size_t)(g16 + srow) * 256 + sseg * 8;
        const int gcol = w * 128 + wave * 16 + l15;    // glin column owned by this lane
        const _Float16* BglBase = Whh16 + (size_t)gcol * 512 + kq * 8;
        const float bbgl = bih[gcol] + bhh[gcol];
        uint32_t* partOut = (uint32_t*)partS + (size_t)bid * 1024;  // [16b][64t]

        for (int t = 0; t < 64; ++t) {
            if (t) wait_flags(fP, 8, (uint32_t)t);     // all 8 pairs published Ab(t)
            // ---- stage A (32 KB) cooperatively from LLC ----
            uint64_t v[8];
#pragma unroll
            for (int i = 0; i < 8; ++i) v[i] = ald64(asrc + i);
#pragma unroll
            for (int q = 0; q < 4; ++q)
                *(v8h*)(Atile + sseg * 512 + q * 128 + srow * 8) = mkv8(v[2 * q], v[2 * q + 1]);
            __syncthreads();

            // ---- s-slice MFMA: wave owns ksegs [4*wave, +4), 2 n-tiles ----
            v4f accs0 = {}, accs1 = {};
#pragma unroll
            for (int kk2 = 0; kk2 < 4; ++kk2) {
                const int kk = wave * 4 + kk2;
                const v8h a = *(const v8h*)(Atile + kk * 512 + kq * 128 + l15 * 8);
                const v8h b0 = *(const v8h*)(Wa1a + (size_t)(w * 32 + l15) * 1024 + kk * 32 + kq * 8);
                const v8h b1 = *(const v8h*)(Wa1a + (size_t)(w * 32 + 16 + l15) * 1024 + kk * 32 + kq * 8);
                accs0 = __builtin_amdgcn_mfma_f32_16x16x32_f16(a, b0, accs0, 0, 0, 0);
                accs1 = __builtin_amdgcn_mfma_f32_16x16x32_f16(a, b1, accs1, 0, 0, 0);
            }
#pragma unroll
            for (int rr = 0; rr < 4; ++rr) {
                sRed[wave * 512 + (kq * 4 + rr) * 32 + l15] = accs0[rr];
                sRed[wave * 512 + (kq * 4 + rr) * 32 + 16 + l15] = accs1[rr];
            }
            __syncthreads();
            {   // reduce 8 K-partials -> s_tile[b][e]
                float ssum = 0.0f;
#pragma unroll
                for (int wv = 0; wv < 8; ++wv) ssum += sRed[wv * 512 + tid];
                s_tile[tid] = ssum;
            }
            __syncthreads();

            // ---- tanh score partials over e-slice: 2 (b,t) combos per thread ----
#pragma unroll
            for (int cc = 0; cc < 2; ++cc) {
                const int cmb = tid + cc * 512;
                const int b = cmb >> 6, tt = cmb & 63;
                const _Float16* hxp = hx + ((size_t)(g16 + b) * 64 + tt) * 512 + w * 32;
                v8h hv[4];
#pragma unroll
                for (int q = 0; q < 4; ++q) hv[q] = *(const v8h*)(hxp + q * 8);
                float acc = 0.0f;
#pragma unroll
                for (int q = 0; q < 4; ++q)
#pragma unroll
                    for (int j = 0; j < 8; ++j)
                        acc += w2l[q * 8 + j] *
                               fast_tanh(s_tile[b * 32 + q * 8 + j] + (float)hv[q][j]);
                ast32(partOut + (size_t)b * 64 + tt, __builtin_bit_cast(uint32_t, acc));
            }
            set_flag(fWA, (uint32_t)(t + 1));

            // ---- glin slice: full K=512 chain, 1 n-tile per wave ----
            v4f accg = {};
#pragma unroll
            for (int kk = 0; kk < 16; ++kk) {
                const v8h a = *(const v8h*)(Atile + kk * 512 + kq * 128 + l15 * 8);
                accg = __builtin_amdgcn_mfma_f32_16x16x32_f16(
                    a, *(const v8h*)(BglBase + kk * 32), accg, 0, 0, 0);
            }
#pragma unroll
            for (int rr = 0; rr < 4; ++rr)
                ast32((uint32_t*)glin + (size_t)(g16 + kq * 4 + rr) * 2048 + gcol,
                      __builtin_bit_cast(uint32_t, accg[rr] + bbgl));
            set_flag(fWB, (uint32_t)(t + 1));
        }
    } else {
        // ------------------ pair blocks ------------------
        const int p = bid - 192, b0 = 2 * p, r = p >> 3;
        uint32_t* fP = ctrs + p * 32;
        const uint32_t* fWA = ctrs + (64 + r * 16) * 32;
        const uint32_t* fWB = ctrs + (192 + r * 16) * 32;
        const float wih_i = Wih[tid], wih_f = Wih[512 + tid],
                    wih_g = Wih[1024 + tid], wih_o = Wih[1536 + tid];
        uint32_t* Abu = (uint32_t*)Ab;
        const int bloc0 = b0 & 15;                     // local batch base in group

        for (int t = 0; t < 64; ++t) {
            wait_flags(fWA, 16, (uint32_t)(t + 1));    // all 16 workers' partials
            {   // sum 16 worker partials per (b,t): 4 threads per combo
                const int cmb = tid >> 2, wq = tid & 3;
                const int blv = cmb >> 6, tt = cmb & 63;
                const int bloc = bloc0 + blv;
                float acc = 0.0f;
#pragma unroll
                for (int i = 0; i < 4; ++i) {
                    const int wi = r * 16 + wq * 4 + i;
                    acc += __builtin_bit_cast(float,
                        ald32((const uint32_t*)partS + ((size_t)wi * 16 + bloc) * 64 + tt));
                }
                acc += __shfl_xor(acc, 1, 64);
                acc += __shfl_xor(acc, 2, 64);
                if (wq == 0) sc[cmb] = acc;
            }
            __syncthreads();

            // ---- joint softmax over the pair's 128 scores ----
            if (tid < 64) {
                float m2 = fmaxf(sc[tid], sc[tid + 64]);
#pragma unroll
                for (int off = 32; off; off >>= 1) m2 = fmaxf(m2, __shfl_xor(m2, off, 64));
                float e0v = __expf(sc[tid] - m2);
                float e1v = __expf(sc[tid + 64] - m2);
                sc[tid] = e0v; sc[tid + 64] = e1v;
                float ssum = e0v + e1v;
#pragma unroll
                for (int off = 32; off; off >>= 1) ssum += __shfl_xor(ssum, off, 64);
                if (tid == 0) red0 = 1.0f / ssum;
            }
            __syncthreads();
            const float inv = red0;

            // ---- context from Xe16[b][t][m] (L2-cached) ----
            {
                const int blv = tid >> 8, m2 = (tid & 255) * 2;
                const uint32_t* xb = (const uint32_t*)(Xe16 + ((size_t)(b0 + blv) * 64) * 512 + m2);
                float a0 = 0.0f, a1 = 0.0f;
#pragma unroll 8
                for (int tt = 0; tt < 64; ++tt) {
                    h2v xv = __builtin_bit_cast(h2v, xb[(size_t)tt * 256]);
                    float bta = sc[blv * 64 + tt];
                    a0 += bta * (float)xv[0];
                    a1 += bta * (float)xv[1];
                }
                ctxl[blv][m2] = a0 * inv;
                ctxl[blv][m2 + 1] = a1 * inv;
            }
            __syncthreads();

            // ---- y_tilde ----
            if (tid < 128) {
                const int blv = tid >> 6, l2 = tid & 63;
                float acc = 0.0f;
#pragma unroll
                for (int j = 0; j < 8; ++j) acc += ctxl[blv][l2 * 8 + j] * Wfc[l2 * 8 + j];
#pragma unroll
                for (int off = 32; off; off >>= 1) acc += __shfl_xor(acc, off, 64);
                if (l2 == 0)
                    ytl[blv] = acc + Wfc[512] * ypr[(size_t)(b0 + blv) * 64 + t] + bfc[0];
            }

            // ---- glin(t) + gates + LSTM update (overlapped gl-GEMM) ----
            wait_flags(fWB, 16, (uint32_t)(t + 1));    // also publishes ytl
            {
                const int pp = tid;
#pragma unroll
                for (int blv = 0; blv < 2; ++blv) {
                    const uint32_t* gb = (const uint32_t*)glin + (size_t)(b0 + blv) * 2048 + pp;
                    const float yt = ytl[blv];
                    float ii = __builtin_bit_cast(float, ald32(gb)) + yt * wih_i;
                    float ff = __builtin_bit_cast(float, ald32(gb + 512)) + yt * wih_f;
                    float ggv = __builtin_bit_cast(float, ald32(gb + 1024)) + yt * wih_g;
                    float oo = __builtin_bit_cast(float, ald32(gb + 1536)) + yt * wih_o;
                    float cprev = cstL[blv][pp];
                    float cn = fast_sigmoid(ff) * cprev + fast_sigmoid(ii) * fast_tanh(ggv);
                    float dn = fast_sigmoid(oo) * fast_tanh(cn);
                    cstL[blv][pp] = cn;
                    dstL[blv][pp] = dn;
                }
            }
            __syncthreads();
            // ---- publish Ab = [d|c] f16 (agent stores) ----
#pragma unroll
            for (int it = 0; it < 2; ++it) {
                int idx = tid + it * 512;              // 1024 u32 items
                int blv = idx >> 9, half = (idx >> 8) & 1, jj = idx & 255;
                float x0 = half ? cstL[blv][jj * 2] : dstL[blv][jj * 2];
                float x1 = half ? cstL[blv][jj * 2 + 1] : dstL[blv][jj * 2 + 1];
                ast32(Abu + (size_t)(b0 + blv) * 512 + half * 256 + jj, packh(x0, x1));
            }
            if (t == 63 && tid < 128) {
                const int blv = tid >> 6, l2 = tid & 63;
                float acc = 0.0f;
#pragma unroll
                for (int j = 0; j < 8; ++j) {
                    int e = l2 * 8 + j;
                    acc += dstL[blv][e] * Wfin[e] + ctxl[blv][e] * Wfin[512 + e];
                }
#pragma unroll
                for (int off = 32; off; off >>= 1) acc += __shfl_xor(acc, off, 64);
                if (l2 == 0) out[b0 + blv] = acc + bfin[0];
            }
            set_flag(fP, (uint32_t)(t + 1));           // Ab(t+1) published
        }
    }
}

extern "C" void kernel_launch(void* const* d_in, const int* in_sizes, int n_in,
                              void* d_out, int out_size, void* d_ws, size_t ws_size,
                              hipStream_t stream)
{
    const float* Xe   = (const float*)d_in[0];
    const float* ypr  = (const float*)d_in[1];
    const float* Wa1  = (const float*)d_in[2];
    const float* ba1  = (const float*)d_in[3];
    const float* Wa2  = (const float*)d_in[4];
    const float* ba2  = (const float*)d_in[5];
    const float* Wih  = (const float*)d_in[6];
    const float* Whh  = (const float*)d_in[7];
    const float* bih  = (const float*)d_in[8];
    const float* bhh  = (const float*)d_in[9];
    const float* Wfc  = (const float*)d_in[10];
    const float* bfc  = (const float*)d_in[11];
    const float* Wfin = (const float*)d_in[12];
    const float* bfin = (const float*)d_in[13];
    float* out = (float*)d_out;

    char* w = (char*)d_ws;
    uint32_t* ctrs  = (uint32_t*)w;                 w += 65536;                       // 64 KB (40 used)
    _Float16* Ab    = (_Float16*)w;                 w += (size_t)128 * 1024 * 2;      // 256 KB
    float*    glin  = (float*)w;                    w += (size_t)128 * 2048 * 4;      // 1 MB
    float*    partS = (float*)w;                    w += (size_t)128 * 16 * 64 * 4;   // 512 KB
    _Float16* Xe16  = (_Float16*)w;                 w += (size_t)8192 * 512 * 2;      // 8 MB
    _Float16* hx    = (_Float16*)w;                 w += (size_t)8192 * 512 * 2;      // 8 MB
    _Float16* Wa1a  = (_Float16*)w;                 w += (size_t)512 * 1024 * 2;      // 1 MB
    _Float16* Whh16 = (_Float16*)w;                 w += (size_t)2048 * 512 * 2;      // 2 MB

    void* args[] = {
        (void*)&Xe, (void*)&ypr, (void*)&Wa1, (void*)&ba1, (void*)&Wa2, (void*)&ba2,
        (void*)&Wih, (void*)&Whh, (void*)&bih, (void*)&bhh, (void*)&Wfc, (void*)&bfc,
        (void*)&Wfin, (void*)&bfin, (void*)&out,
        (void*)&ctrs, (void*)&Ab, (void*)&glin, (void*)&partS, (void*)&Xe16, (void*)&hx,
        (void*)&Wa1a, (void*)&Whh16
    };
    hipLaunchCooperativeKernel((const void*)fused_decoder, dim3(256), dim3(512),
                               args, 0, stream);
}

// Round 9
// 1334.271 us; speedup vs baseline: 4.8075x; 1.0102x over previous
//
#include <hip/hip_runtime.h>
#include <hip/hip_cooperative_groups.h>

namespace cg = cooperative_groups;

// Problem sizes (fixed): B=128, Tm1=64, M=P=512
typedef _Float16 v8h __attribute__((ext_vector_type(8)));
typedef _Float16 h2v __attribute__((ext_vector_type(2)));
typedef float v4f __attribute__((ext_vector_type(4)));

#define SCOPE_AGENT __HIP_MEMORY_SCOPE_AGENT

static __device__ __forceinline__ uint32_t ald32(const uint32_t* p) {
    return __hip_atomic_load(p, __ATOMIC_RELAXED, SCOPE_AGENT);
}
static __device__ __forceinline__ uint64_t ald64(const uint64_t* p) {
    return __hip_atomic_load(p, __ATOMIC_RELAXED, SCOPE_AGENT);
}
static __device__ __forceinline__ void ast32(uint32_t* p, uint32_t v) {
    __hip_atomic_store(p, v, __ATOMIC_RELAXED, SCOPE_AGENT);
}
static __device__ __forceinline__ v8h mkv8(uint64_t lo, uint64_t hi) {
    union { uint64_t q[2]; v8h h; } u; u.q[0] = lo; u.q[1] = hi; return u.h;
}
static __device__ __forceinline__ uint32_t packh(float a, float b) {
    uint16_t ua = __builtin_bit_cast(uint16_t, (_Float16)a);
    uint16_t ub = __builtin_bit_cast(uint16_t, (_Float16)b);
    return (uint32_t)ua | ((uint32_t)ub << 16);
}
static __device__ __forceinline__ float fast_tanh(float x) {
    float e = __expf(2.0f * x);
    return 1.0f - 2.0f / (e + 1.0f);
}
static __device__ __forceinline__ float fast_sigmoid(float x) {
    return 1.0f / (1.0f + __expf(-x));
}
static __device__ __forceinline__ v8h cvt8(const float* p) {
    float4 a = *(const float4*)p;
    float4 b = *(const float4*)(p + 4);
    v8h h;
    h[0] = (_Float16)a.x; h[1] = (_Float16)a.y; h[2] = (_Float16)a.z; h[3] = (_Float16)a.w;
    h[4] = (_Float16)b.x; h[5] = (_Float16)b.y; h[6] = (_Float16)b.z; h[7] = (_Float16)b.w;
    return h;
}

// ---- single-writer flag lines (128 B apart); wave-parallel polling ----
static __device__ __forceinline__ void set_flag(uint32_t* line, uint32_t v) {
    asm volatile("s_waitcnt vmcnt(0)" ::: "memory");
    __syncthreads();
    if (threadIdx.x == 0) ast32(line, v);
}
static __device__ __forceinline__ void wait_flags(const uint32_t* base, int n, uint32_t target) {
    if (threadIdx.x < 64) {
        const uint32_t* p = base + (threadIdx.x & (n - 1)) * 32;
        while (ald32(p) < target) __builtin_amdgcn_s_sleep(1);
    }
    __syncthreads();
    asm volatile("" ::: "memory");
}

// Grid: 256 blocks x 512 threads, cooperative (1 block/CU).
// 8 groups, group r = batches [16r, +16):
//   workers bid 0..127 (r=bid>>4, w=bid&15): s-slice cols[32w,+32) K-split-8,
//     tanh score partials (hx-slice in LDS), then glin cols[128w,+128) K-split-8.
//   bid 128..191: prologue only.
//   pairs bid 192..255 (p=bid-192): Xe-slice in LDS; softmax/context/ytilde/gates.
// Flags: fP[p] @ p*32 ; fWA[bid] @ (64+bid)*32 ; fWB[bid] @ (192+bid)*32
__global__ __launch_bounds__(512, 2) void fused_decoder(
    const float* __restrict__ Xe, const float* __restrict__ ypr,
    const float* __restrict__ Wa1, const float* __restrict__ ba1,
    const float* __restrict__ Wa2, const float* __restrict__ ba2,
    const float* __restrict__ Wih, const float* __restrict__ Whh,
    const float* __restrict__ bih, const float* __restrict__ bhh,
    const float* __restrict__ Wfc, const float* __restrict__ bfc,
    const float* __restrict__ Wfin, const float* __restrict__ bfin,
    float* __restrict__ out,
    uint32_t* __restrict__ ctrs,          // 320 flag lines
    _Float16* __restrict__ Ab,            // [128][1024] (d|c) f16 — agent-only
    float* __restrict__ glin,             // [128][2048] f32 (+biases) — agent-only
    float* __restrict__ partS,            // [64 p][16 w][2 b][64 t] f32 — agent-only
    _Float16* __restrict__ hx,            // [8192][512] f16
    _Float16* __restrict__ Wa1a,          // [512][1024] f16
    _Float16* __restrict__ Whh16)         // [2048][512] f16
{
    cg::grid_group gg = cg::this_grid();
    const int bid = blockIdx.x;
    const int tid = threadIdx.x;
    const int wave = tid >> 6, lane = tid & 63;
    const int l15 = lane & 15, kq = lane >> 4;
    const int gt = bid * 512 + tid;

    __shared__ __align__(16) char arena[143888];

    // ===== sync #1: flush poison-dirty ws lines from all L2s =====
    gg.sync();

    // ===== prologue: all NORMAL stores, 128B-line-owned per thread =====
    if (gt < 8192) {                       // Wa1a [512][1024] <- Wa1[:,0:1024)
        int row = gt >> 4, seg = gt & 15;
        const float* src = Wa1 + (size_t)row * 1536 + seg * 64;
        _Float16* dp = Wa1a + (size_t)row * 1024 + seg * 64;
#pragma unroll
        for (int i = 0; i < 8; ++i) *(v8h*)(dp + i * 8) = cvt8(src + i * 8);
    } else if (gt < 24576) {               // Whh16 [2048][512]
        int u = gt - 8192;
        int row = u >> 3, seg = u & 7;
        const float* src = Whh + (size_t)row * 512 + seg * 64;
        _Float16* dp = Whh16 + (size_t)row * 512 + seg * 64;
#pragma unroll
        for (int i = 0; i < 8; ++i) *(v8h*)(dp + i * 8) = cvt8(src + i * 8);
    } else if (gt < 26624) {               // Ab zero: 2048 lines x 16 u64
        uint64_t* p = (uint64_t*)Ab + (size_t)(gt - 24576) * 16;
#pragma unroll
        for (int i = 0; i < 16; ++i) p[i] = 0ull;
    } else if (gt < 36864) {               // flags zero: 10240 u32
        ctrs[gt - 26624] = 0u;
    }
    // hx = f16(Xe @ Wa1[:,1024:]^T + ba1) — all 256 blocks
    {
        const int wg = bid * 8 + wave;                 // 0..2047
        const int mt = wg >> 2;                        // row tile 0..511
        const int nq = wg & 3;
        const float* Abase = Xe + (size_t)(mt * 16 + l15) * 512 + kq * 8;
        v8h afr[16];
#pragma unroll
        for (int ks = 0; ks < 16; ++ks) afr[ks] = cvt8(Abase + ks * 32);
#pragma unroll
        for (int i = 0; i < 8; ++i) {
            const int nt = nq * 8 + i;
            const float* Bbase = Wa1 + (size_t)(nt * 16 + l15) * 1536 + 1024 + kq * 8;
            v4f acc = {};
#pragma unroll 4
            for (int ks = 0; ks < 16; ++ks)
                acc = __builtin_amdgcn_mfma_f32_16x16x32_f16(afr[ks], cvt8(Bbase + ks * 32), acc, 0, 0, 0);
            const float bav = ba1[nt * 16 + l15];
            _Float16* hrow = hx + (size_t)(mt * 16 + kq * 4) * 512 + nt * 16 + l15;
#pragma unroll
            for (int r = 0; r < 4; ++r) hrow[(size_t)r * 512] = (_Float16)(acc[r] + bav);
        }
    }
    // ===== sync #2: publish all prologue data; all L2s clean =====
    gg.sync();

    if (bid >= 128 && bid < 192) return;

    // =========================== main recurrence =============================
    if (bid < 128) {
        // ------------------ worker blocks ------------------
        const int r = bid >> 4, w = bid & 15;
        const int g16 = r * 16;
        uint32_t* fWA = ctrs + (64 + bid) * 32;
        uint32_t* fWB = ctrs + (192 + bid) * 32;
        const uint32_t* fP = ctrs + (r * 8) * 32;
        _Float16* hxL = (_Float16*)arena;               // 64 KB, chunk-swizzled
        float* red = (float*)(arena + 65536);           // 64 KB (sRed / sRedG)
        float* s_tile = (float*)(arena + 131072);       // 2 KB
        float* w2l = (float*)(arena + 133120);          // 128 B

        // one-time: hx slice -> LDS (chunk XOR swizzle by (tt>>1)&3)
        for (int cmb = tid; cmb < 1024; cmb += 512) {
            const int b = cmb >> 6, tt = cmb & 63, sw = (tt >> 1) & 3;
            const _Float16* src = hx + ((size_t)(g16 + b) * 64 + tt) * 512 + w * 32;
#pragma unroll
            for (int c = 0; c < 4; ++c)
                *(v8h*)(hxL + (size_t)cmb * 32 + ((c ^ sw) << 3)) = *(const v8h*)(src + c * 8);
        }
        if (tid < 32) w2l[tid] = Wa2[w * 32 + tid];
        __syncthreads();

        const uint64_t* abase = (const uint64_t*)Ab + (size_t)(g16 + l15) * 256 + kq * 2;
        const _Float16* Bs0 = Wa1a + (size_t)(w * 32 + l15) * 1024 + kq * 8;
        const _Float16* Bs1 = Wa1a + (size_t)(w * 32 + 16 + l15) * 1024 + kq * 8;
        float bbv[4];
#pragma unroll
        for (int j = 0; j < 4; ++j) {
            const int gcol = w * 128 + ((tid + j * 512) & 127);
            bbv[j] = bih[gcol] + bhh[gcol];
        }
        uint32_t* partB = (uint32_t*)partS;

        for (int t = 0; t < 64; ++t) {
            if (t) wait_flags(fP, 8, (uint32_t)t);
            // ---- s-slice: wave owns ksegs [4w,+4), frags straight from LLC ----
            v8h Af[4];
#pragma unroll
            for (int k2 = 0; k2 < 4; ++k2) {
                const int kk = wave * 4 + k2;
                Af[k2] = mkv8(ald64(abase + kk * 8), ald64(abase + kk * 8 + 1));
            }
            v4f a0 = {}, a1 = {};
#pragma unroll
            for (int k2 = 0; k2 < 4; ++k2) {
                const int kk = wave * 4 + k2;
                a0 = __builtin_amdgcn_mfma_f32_16x16x32_f16(Af[k2], *(const v8h*)(Bs0 + kk * 32), a0, 0, 0, 0);
                a1 = __builtin_amdgcn_mfma_f32_16x16x32_f16(Af[k2], *(const v8h*)(Bs1 + kk * 32), a1, 0, 0, 0);
            }
#pragma unroll
            for (int rr = 0; rr < 4; ++rr) {
                red[wave * 512 + (kq * 4 + rr) * 32 + l15] = a0[rr];
                red[wave * 512 + (kq * 4 + rr) * 32 + 16 + l15] = a1[rr];
            }
            __syncthreads();
            {
                float ssum = 0.0f;
#pragma unroll
                for (int wv = 0; wv < 8; ++wv) ssum += red[wv * 512 + tid];
                s_tile[tid] = ssum;
            }
            __syncthreads();

            // ---- tanh score partials: 2 (b,t) combos per thread, hx from LDS ----
#pragma unroll
            for (int cc = 0; cc < 2; ++cc) {
                const int cmb = tid + cc * 512;
                const int b = cmb >> 6, tt = cmb & 63, sw = (tt >> 1) & 3;
                const _Float16* hb = hxL + (size_t)cmb * 32;
                float acc = 0.0f;
#pragma unroll
                for (int q = 0; q < 4; ++q) {
                    const v8h hv = *(const v8h*)(hb + ((q ^ sw) << 3));
#pragma unroll
                    for (int j = 0; j < 8; ++j)
                        acc += w2l[q * 8 + j] *
                               fast_tanh(s_tile[b * 32 + q * 8 + j] + (float)hv[j]);
                }
                const int pg = r * 8 + (b >> 1);
                ast32(partB + (((size_t)pg * 16 + w) * 2 + (b & 1)) * 64 + tt,
                      __builtin_bit_cast(uint32_t, acc));
            }
            set_flag(fWA, (uint32_t)(t + 1));

            // ---- glin: wave owns d-ksegs [2w,+2); K-split-8 + LDS reduce ----
            v8h Ag[2];
#pragma unroll
            for (int i = 0; i < 2; ++i) {
                const int kk = wave * 2 + i;
                Ag[i] = mkv8(ald64(abase + kk * 8), ald64(abase + kk * 8 + 1));
            }
#pragma unroll
            for (int nt = 0; nt < 8; ++nt) {
                const _Float16* Bg = Whh16 + (size_t)(w * 128 + nt * 16 + l15) * 512 + kq * 8;
                v4f ag = {};
#pragma unroll
                for (int i = 0; i < 2; ++i)
                    ag = __builtin_amdgcn_mfma_f32_16x16x32_f16(
                        Ag[i], *(const v8h*)(Bg + (wave * 2 + i) * 32), ag, 0, 0, 0);
#pragma unroll
                for (int rr = 0; rr < 4; ++rr)
                    red[wave * 2048 + (kq * 4 + rr) * 128 + nt * 16 + l15] = ag[rr];
            }
            __syncthreads();
#pragma unroll
            for (int j = 0; j < 4; ++j) {
                const int o = tid + j * 512;           // row*128+col
                float g = 0.0f;
#pragma unroll
                for (int wv = 0; wv < 8; ++wv) g += red[wv * 2048 + o];
                ast32((uint32_t*)glin + (size_t)(g16 + (o >> 7)) * 2048 + w * 128 + (o & 127),
                      __builtin_bit_cast(uint32_t, g + bbv[j]));
            }
            set_flag(fWB, (uint32_t)(t + 1));
        }
    } else {
        // ------------------ pair blocks ------------------
        const int p = bid - 192, b0 = 2 * p, r = p >> 3;
        uint32_t* fP = ctrs + p * 32;
        const uint32_t* fWA = ctrs + (64 + r * 16) * 32;
        const uint32_t* fWB = ctrs + (192 + r * 16) * 32;
        _Float16* XeL = (_Float16*)arena;               // 128 KB
        float* sc = (float*)(arena + 131072);
        float* dstL = (float*)(arena + 131584);         // [2][512]
        float* cstL = (float*)(arena + 135680);
        float* ctxl = (float*)(arena + 139776);
        float* ytl = (float*)(arena + 143872);
        float* red0 = (float*)(arena + 143880);

        // one-time: Xe slice (2 batches) -> LDS f16
        {
            const float* xsrc = Xe + (size_t)b0 * 64 * 512;
#pragma unroll
            for (int i = 0; i < 16; ++i) {
                const int u = tid + i * 512;
                *(v8h*)(XeL + (size_t)u * 8) = cvt8(xsrc + (size_t)u * 8);
            }
        }
        for (int i = tid; i < 1024; i += 512) { dstL[i] = 0.0f; cstL[i] = 0.0f; }
        const float wih_i = Wih[tid], wih_f = Wih[512 + tid],
                    wih_g = Wih[1024 + tid], wih_o = Wih[1536 + tid];
        uint32_t* Abu = (uint32_t*)Ab;
        const uint32_t* partB = (const uint32_t*)partS;
        __syncthreads();

        for (int t = 0; t < 64; ++t) {
            wait_flags(fWA, 16, (uint32_t)(t + 1));
            {   // sum 16 worker partials per (b,t): 4 threads per combo
                const int cmb = tid >> 2, wq = tid & 3;
                const int blv = cmb >> 6, tt = cmb & 63;
                float acc = 0.0f;
#pragma unroll
                for (int i = 0; i < 4; ++i)
                    acc += __builtin_bit_cast(float,
                        ald32(partB + (((size_t)p * 16 + wq * 4 + i) * 2 + blv) * 64 + tt));
                acc += __shfl_xor(acc, 1, 64);
                acc += __shfl_xor(acc, 2, 64);
                if (wq == 0) sc[cmb] = acc;
            }
            __syncthreads();

            // ---- joint softmax over the pair's 128 scores ----
            if (tid < 64) {
                float m2 = fmaxf(sc[tid], sc[tid + 64]);
#pragma unroll
                for (int off = 32; off; off >>= 1) m2 = fmaxf(m2, __shfl_xor(m2, off, 64));
                float e0v = __expf(sc[tid] - m2);
                float e1v = __expf(sc[tid + 64] - m2);
                sc[tid] = e0v; sc[tid + 64] = e1v;
                float ssum = e0v + e1v;
#pragma unroll
                for (int off = 32; off; off >>= 1) ssum += __shfl_xor(ssum, off, 64);
                if (tid == 0) red0[0] = 1.0f / ssum;
            }
            __syncthreads();
            const float inv = red0[0];

            // ---- context from XeL (LDS) ----
            {
                const int blv = tid >> 8, m2 = (tid & 255) * 2;
                const _Float16* xb = XeL + (size_t)blv * 64 * 512 + m2;
                float a0 = 0.0f, a1 = 0.0f;
#pragma unroll 8
                for (int tt = 0; tt < 64; ++tt) {
                    const h2v xv = *(const h2v*)(xb + (size_t)tt * 512);
                    const float bta = sc[blv * 64 + tt];
                    a0 += bta * (float)xv[0];
                    a1 += bta * (float)xv[1];
                }
                ctxl[blv * 512 + m2] = a0 * inv;
                ctxl[blv * 512 + m2 + 1] = a1 * inv;
            }
            __syncthreads();

            // ---- wait glin, issue gate loads early, ytilde in the shadow ----
            wait_flags(fWB, 16, (uint32_t)(t + 1));
            uint32_t gi[2], gf[2], gg2[2], go[2];
#pragma unroll
            for (int blv = 0; blv < 2; ++blv) {
                const uint32_t* gb = (const uint32_t*)glin + (size_t)(b0 + blv) * 2048 + tid;
                gi[blv] = ald32(gb);
                gf[blv] = ald32(gb + 512);
                gg2[blv] = ald32(gb + 1024);
                go[blv] = ald32(gb + 1536);
            }
            if (tid < 128) {
                const int blv = tid >> 6, l2 = tid & 63;
                float acc = 0.0f;
#pragma unroll
                for (int j = 0; j < 8; ++j) acc += ctxl[blv * 512 + l2 * 8 + j] * Wfc[l2 * 8 + j];
#pragma unroll
                for (int off = 32; off; off >>= 1) acc += __shfl_xor(acc, off, 64);
                if (l2 == 0)
                    ytl[blv] = acc + Wfc[512] * ypr[(size_t)(b0 + blv) * 64 + t] + bfc[0];
            }
            __syncthreads();

            // ---- gates + LSTM update ----
#pragma unroll
            for (int blv = 0; blv < 2; ++blv) {
                const float yt = ytl[blv];
                float ii = __builtin_bit_cast(float, gi[blv]) + yt * wih_i;
                float ff = __builtin_bit_cast(float, gf[blv]) + yt * wih_f;
                float ggv = __builtin_bit_cast(float, gg2[blv]) + yt * wih_g;
                float oo = __builtin_bit_cast(float, go[blv]) + yt * wih_o;
                float cprev = cstL[blv * 512 + tid];
                float cn = fast_sigmoid(ff) * cprev + fast_sigmoid(ii) * fast_tanh(ggv);
                float dn = fast_sigmoid(oo) * fast_tanh(cn);
                cstL[blv * 512 + tid] = cn;
                dstL[blv * 512 + tid] = dn;
            }
            __syncthreads();
            // ---- publish Ab = [d|c] f16 ----
#pragma unroll
            for (int it = 0; it < 2; ++it) {
                const int idx = tid + it * 512;
                const int blv = idx >> 9, half = (idx >> 8) & 1, jj = idx & 255;
                const float x0 = half ? cstL[blv * 512 + jj * 2] : dstL[blv * 512 + jj * 2];
                const float x1 = half ? cstL[blv * 512 + jj * 2 + 1] : dstL[blv * 512 + jj * 2 + 1];
                ast32(Abu + (size_t)(b0 + blv) * 512 + half * 256 + jj, packh(x0, x1));
            }
            if (t == 63 && tid < 128) {
                const int blv = tid >> 6, l2 = tid & 63;
                float acc = 0.0f;
#pragma unroll
                for (int j = 0; j < 8; ++j) {
                    const int e = l2 * 8 + j;
                    acc += dstL[blv * 512 + e] * Wfin[e] + ctxl[blv * 512 + e] * Wfin[512 + e];
                }
#pragma unroll
                for (int off = 32; off; off >>= 1) acc += __shfl_xor(acc, off, 64);
                if (l2 == 0) out[b0 + blv] = acc + bfin[0];
            }
            set_flag(fP, (uint32_t)(t + 1));
        }
    }
}

extern "C" void kernel_launch(void* const* d_in, const int* in_sizes, int n_in,
                              void* d_out, int out_size, void* d_ws, size_t ws_size,
                              hipStream_t stream)
{
    const float* Xe   = (const float*)d_in[0];
    const float* ypr  = (const float*)d_in[1];
    const float* Wa1  = (const float*)d_in[2];
    const float* ba1  = (const float*)d_in[3];
    const float* Wa2  = (const float*)d_in[4];
    const float* ba2  = (const float*)d_in[5];
    const float* Wih  = (const float*)d_in[6];
    const float* Whh  = (const float*)d_in[7];
    const float* bih  = (const float*)d_in[8];
    const float* bhh  = (const float*)d_in[9];
    const float* Wfc  = (const float*)d_in[10];
    const float* bfc  = (const float*)d_in[11];
    const float* Wfin = (const float*)d_in[12];
    const float* bfin = (const float*)d_in[13];
    float* out = (float*)d_out;

    char* w = (char*)d_ws;
    uint32_t* ctrs  = (uint32_t*)w;                 w += 65536;                       // 64 KB (40 used)
    _Float16* Ab    = (_Float16*)w;                 w += (size_t)128 * 1024 * 2;      // 256 KB
    float*    glin  = (float*)w;                    w += (size_t)128 * 2048 * 4;      // 1 MB
    float*    partS = (float*)w;                    w += (size_t)64 * 16 * 2 * 64 * 4; // 512 KB
    _Float16* hx    = (_Float16*)w;                 w += (size_t)8192 * 512 * 2;      // 8 MB
    _Float16* Wa1a  = (_Float16*)w;                 w += (size_t)512 * 1024 * 2;      // 1 MB
    _Float16* Whh16 = (_Float16*)w;                 w += (size_t)2048 * 512 * 2;      // 2 MB

    void* args[] = {
        (void*)&Xe, (void*)&ypr, (void*)&Wa1, (void*)&ba1, (void*)&Wa2, (void*)&ba2,
        (void*)&Wih, (void*)&Whh, (void*)&bih, (void*)&bhh, (void*)&Wfc, (void*)&bfc,
        (void*)&Wfin, (void*)&bfin, (void*)&out,
        (void*)&ctrs, (void*)&Ab, (void*)&glin, (void*)&partS, (void*)&hx,
        (void*)&Wa1a, (void*)&Whh16
    };
    hipLaunchCooperativeKernel((const void*)fused_decoder, dim3(256), dim3(512),
                               args, 0, stream);
}

// Round 12
// 1296.211 us; speedup vs baseline: 4.9487x; 1.0294x over previous
//
#include <hip/hip_runtime.h>
#include <hip/hip_cooperative_groups.h>

namespace cg = cooperative_groups;

// Problem sizes (fixed): B=128, Tm1=64, M=P=512
typedef _Float16 v8h __attribute__((ext_vector_type(8)));
typedef _Float16 h2v __attribute__((ext_vector_type(2)));
typedef float v4f __attribute__((ext_vector_type(4)));

#define SCOPE_AGENT __HIP_MEMORY_SCOPE_AGENT

static __device__ __forceinline__ uint32_t ald32(const uint32_t* p) {
    return __hip_atomic_load(p, __ATOMIC_RELAXED, SCOPE_AGENT);
}
static __device__ __forceinline__ uint64_t ald64(const uint64_t* p) {
    return __hip_atomic_load(p, __ATOMIC_RELAXED, SCOPE_AGENT);
}
static __device__ __forceinline__ void ast32(uint32_t* p, uint32_t v) {
    __hip_atomic_store(p, v, __ATOMIC_RELAXED, SCOPE_AGENT);
}
static __device__ __forceinline__ v8h mkv8(uint64_t lo, uint64_t hi) {
    union { uint64_t q[2]; v8h h; } u; u.q[0] = lo; u.q[1] = hi; return u.h;
}
static __device__ __forceinline__ uint32_t packh(float a, float b) {
    uint16_t ua = __builtin_bit_cast(uint16_t, (_Float16)a);
    uint16_t ub = __builtin_bit_cast(uint16_t, (_Float16)b);
    return (uint32_t)ua | ((uint32_t)ub << 16);
}
static __device__ __forceinline__ float fast_tanh(float x) {
    float e = __expf(2.0f * x);
    return 1.0f - 2.0f / (e + 1.0f);
}
static __device__ __forceinline__ float fast_sigmoid(float x) {
    return 1.0f / (1.0f + __expf(-x));
}
static __device__ __forceinline__ v8h cvt8(const float* p) {
    float4 a = *(const float4*)p;
    float4 b = *(const float4*)(p + 4);
    v8h h;
    h[0] = (_Float16)a.x; h[1] = (_Float16)a.y; h[2] = (_Float16)a.z; h[3] = (_Float16)a.w;
    h[4] = (_Float16)b.x; h[5] = (_Float16)b.y; h[6] = (_Float16)b.z; h[7] = (_Float16)b.w;
    return h;
}

// ---- private flag lines: ONE writer block, ONE reader block per 128B line ----
// fP  [g][w][p] : line (g*128 + w*8 + p)            — pair p writes, worker w reads
// fWA [g][p][w] : line FWA + (g*128 + p*16 + w)     — worker w writes, pair p reads
// fWB [g][p][w] : line FWB + (g*128 + p*16 + w)
#define FWA_OFF 32768   // u32 offset (= 1024 lines * 32)
#define FWB_OFF 65536

// poll n private lines (lane i -> line i)
static __device__ __forceinline__ void wait_lines(const uint32_t* base, int n, uint32_t target) {
    if ((int)threadIdx.x < n) {
        const uint32_t* p = base + threadIdx.x * 32;
        while (ald32(p) < target) __builtin_amdgcn_s_sleep(1);
    }
    __syncthreads();
    asm volatile("" ::: "memory");
}
// drain all waves' stores, then lane i stores to line i*stride (i<n)
static __device__ __forceinline__ void publish_lines(uint32_t* base, int n, int stride_u32, uint32_t v) {
    asm volatile("s_waitcnt vmcnt(0)" ::: "memory");   // per-wave drain (ast32 stores hit LLC)
    __syncthreads();                                    // all waves drained
    if ((int)threadIdx.x < n) ast32(base + threadIdx.x * stride_u32, v);
}

// Grid: 256 blocks x 512 threads, cooperative.
// 8 groups, group r = batches [16r,+16):
//   workers bid 0..127 (r=bid>>4, w=bid&15): s-slice cols[32w,+32) K-split-8 +
//     tanh score partials (hx-slice in LDS), then glin cols[128w,+128) K-split-8.
//   bid 128..191: prologue only.
//   pairs bid 192..255 (p=bid-192, r=p>>3, pl=p&7): softmax/context/ytilde/gates.
__global__ __launch_bounds__(512, 2) void fused_decoder(
    const float* __restrict__ Xe, const float* __restrict__ ypr,
    const float* __restrict__ Wa1, const float* __restrict__ ba1,
    const float* __restrict__ Wa2, const float* __restrict__ ba2,
    const float* __restrict__ Wih, const float* __restrict__ Whh,
    const float* __restrict__ bih, const float* __restrict__ bhh,
    const float* __restrict__ Wfc, const float* __restrict__ bfc,
    const float* __restrict__ Wfin, const float* __restrict__ bfin,
    float* __restrict__ out,
    uint32_t* __restrict__ ctrs,          // 3072 private flag lines (384 KB)
    _Float16* __restrict__ Ab,            // [128][1024] (d|c) f16 — agent-only
    float* __restrict__ glin,             // [128][2048] f32 (+biases) — agent-only
    float* __restrict__ partS,            // [64 p][16 w][2 b][64 t] f32 — agent-only
    _Float16* __restrict__ hx,            // [8192][512] f16
    _Float16* __restrict__ Wa1a,          // [512][1024] f16
    _Float16* __restrict__ Whh16)         // [2048][512] f16
{
    cg::grid_group gg = cg::this_grid();
    const int bid = blockIdx.x;
    const int tid = threadIdx.x;
    const int wave = tid >> 6, lane = tid & 63;
    const int l15 = lane & 15, kq = lane >> 4;
    const int gt = bid * 512 + tid;

    __shared__ __align__(16) char arena[143888];

    // ===== sync #1: flush poison-dirty ws lines from all L2s =====
    gg.sync();

    // ===== prologue: NORMAL stores, 128B-line-owned per thread =====
    if (gt < 8192) {                       // Wa1a [512][1024] <- Wa1[:,0:1024)
        int row = gt >> 4, seg = gt & 15;
        const float* src = Wa1 + (size_t)row * 1536 + seg * 64;
        _Float16* dp = Wa1a + (size_t)row * 1024 + seg * 64;
#pragma unroll
        for (int i = 0; i < 8; ++i) *(v8h*)(dp + i * 8) = cvt8(src + i * 8);
    } else if (gt < 24576) {               // Whh16 [2048][512]
        int u = gt - 8192;
        int row = u >> 3, seg = u & 7;
        const float* src = Whh + (size_t)row * 512 + seg * 64;
        _Float16* dp = Whh16 + (size_t)row * 512 + seg * 64;
#pragma unroll
        for (int i = 0; i < 8; ++i) *(v8h*)(dp + i * 8) = cvt8(src + i * 8);
    } else if (gt < 26624) {               // Ab zero: 2048 lines x 16 u64
        uint64_t* p = (uint64_t*)Ab + (size_t)(gt - 24576) * 16;
#pragma unroll
        for (int i = 0; i < 16; ++i) p[i] = 0ull;
    } else if (gt < 124928) {              // flags zero: 98304 u32 (384 KB)
        ctrs[gt - 26624] = 0u;
    }
    // hx = f16(Xe @ Wa1[:,1024:]^T + ba1) — all 256 blocks
    {
        const int wg = bid * 8 + wave;                 // 0..2047
        const int mt = wg >> 2;
        const int nq = wg & 3;
        const float* Abase = Xe + (size_t)(mt * 16 + l15) * 512 + kq * 8;
        v8h afr[16];
#pragma unroll
        for (int ks = 0; ks < 16; ++ks) afr[ks] = cvt8(Abase + ks * 32);
#pragma unroll
        for (int i = 0; i < 8; ++i) {
            const int nt = nq * 8 + i;
            const float* Bbase = Wa1 + (size_t)(nt * 16 + l15) * 1536 + 1024 + kq * 8;
            v4f acc = {};
#pragma unroll 4
            for (int ks = 0; ks < 16; ++ks)
                acc = __builtin_amdgcn_mfma_f32_16x16x32_f16(afr[ks], cvt8(Bbase + ks * 32), acc, 0, 0, 0);
            const float bav = ba1[nt * 16 + l15];
            _Float16* hrow = hx + (size_t)(mt * 16 + kq * 4) * 512 + nt * 16 + l15;
#pragma unroll
            for (int r = 0; r < 4; ++r) hrow[(size_t)r * 512] = (_Float16)(acc[r] + bav);
        }
    }
    // ===== sync #2: publish prologue; all L2s clean =====
    gg.sync();

    if (bid >= 128 && bid < 192) return;

    // =========================== main recurrence =============================
    if (bid < 128) {
        // ------------------ worker: e-slice [32w,+32), glin [128w,+128) ------------------
        const int r = bid >> 4, w = bid & 15;
        const int g16 = r * 16;
        const uint32_t* fPbase = ctrs + (size_t)(r * 128 + w * 8) * 32;     // poll 8
        uint32_t* fWAbase = ctrs + FWA_OFF + (size_t)(r * 128 + w) * 32;    // store stride 16*32
        uint32_t* fWBbase = ctrs + FWB_OFF + (size_t)(r * 128 + w) * 32;
        _Float16* hxL = (_Float16*)arena;               // 64 KB, [c][cmb][8] chunked
        float* red = (float*)(arena + 65536);           // 64 KB
        float* s_tile = (float*)(arena + 131072);       // 2 KB
        float* w2l = (float*)(arena + 133120);          // 128 B

        // one-time: hx slice -> LDS chunked (conflict-free read & write)
        for (int cmb = tid; cmb < 1024; cmb += 512) {
            const int b = cmb >> 6, tt = cmb & 63;
            const _Float16* src = hx + ((size_t)(g16 + b) * 64 + tt) * 512 + w * 32;
#pragma unroll
            for (int c = 0; c < 4; ++c)
                *(v8h*)(hxL + ((size_t)(c * 1024 + cmb) << 3)) = *(const v8h*)(src + c * 8);
        }
        if (tid < 32) w2l[tid] = Wa2[w * 32 + tid];
        __syncthreads();

        const uint64_t* abase = (const uint64_t*)Ab + (size_t)(g16 + l15) * 256 + kq * 2;
        const _Float16* Bs0 = Wa1a + (size_t)(w * 32 + l15) * 1024 + kq * 8;
        const _Float16* Bs1 = Wa1a + (size_t)(w * 32 + 16 + l15) * 1024 + kq * 8;
        float bbv[4];
#pragma unroll
        for (int j = 0; j < 4; ++j) {
            const int gcol = w * 128 + ((tid + j * 512) & 127);
            bbv[j] = bih[gcol] + bhh[gcol];
        }
        uint32_t* partOut = (uint32_t*)partS;

        for (int t = 0; t < 64; ++t) {
            if (t) wait_lines(fPbase, 8, (uint32_t)t);
            // ---- ALL Ab fragment loads upfront (one latency) ----
            uint64_t ls[8], lg[4];
#pragma unroll
            for (int k2 = 0; k2 < 4; ++k2) {
                ls[2 * k2]     = ald64(abase + (wave * 4 + k2) * 8);
                ls[2 * k2 + 1] = ald64(abase + (wave * 4 + k2) * 8 + 1);
            }
#pragma unroll
            for (int i = 0; i < 2; ++i) {
                lg[2 * i]     = ald64(abase + (wave * 2 + i) * 8);
                lg[2 * i + 1] = ald64(abase + (wave * 2 + i) * 8 + 1);
            }
            // ---- s-slice MFMA: wave owns ksegs [4w,+4) ----
            v4f a0 = {}, a1 = {};
#pragma unroll
            for (int k2 = 0; k2 < 4; ++k2) {
                const int kk = wave * 4 + k2;
                const v8h af = mkv8(ls[2 * k2], ls[2 * k2 + 1]);
                a0 = __builtin_amdgcn_mfma_f32_16x16x32_f16(af, *(const v8h*)(Bs0 + kk * 32), a0, 0, 0, 0);
                a1 = __builtin_amdgcn_mfma_f32_16x16x32_f16(af, *(const v8h*)(Bs1 + kk * 32), a1, 0, 0, 0);
            }
#pragma unroll
            for (int rr = 0; rr < 4; ++rr) {
                red[wave * 512 + (kq * 4 + rr) * 32 + l15] = a0[rr];
                red[wave * 512 + (kq * 4 + rr) * 32 + 16 + l15] = a1[rr];
            }
            __syncthreads();
            {
                float ssum = 0.0f;
#pragma unroll
                for (int wv = 0; wv < 8; ++wv) ssum += red[wv * 512 + tid];
                s_tile[tid] = ssum;
            }
            __syncthreads();

            // ---- tanh score partials: 2 (b,t) combos/thread ----
#pragma unroll
            for (int cc = 0; cc < 2; ++cc) {
                const int cmb = tid + cc * 512;
                const int b = cmb >> 6, tt = cmb & 63;
                const _Float16* hb = hxL + ((size_t)cmb << 3);
                float acc = 0.0f;
#pragma unroll
                for (int q = 0; q < 4; ++q) {
                    const v8h hv = *(const v8h*)(hb + ((size_t)q << 13));
#pragma unroll
                    for (int j = 0; j < 8; ++j)
                        acc += w2l[q * 8 + j] *
                               fast_tanh(s_tile[b * 32 + q * 8 + j] + (float)hv[j]);
                }
                const int pg = r * 8 + (b >> 1);
                ast32(partOut + (((size_t)pg * 16 + w) * 2 + (b & 1)) * 64 + tt,
                      __builtin_bit_cast(uint32_t, acc));      // AGENT store -> LLC (the fix)
            }
            publish_lines(fWAbase, 8, 16 * 32, (uint32_t)(t + 1));

            // ---- glin: wave owns d-ksegs [2w,+2); K-split-8 + LDS reduce ----
            v8h Ag[2];
#pragma unroll
            for (int i = 0; i < 2; ++i) Ag[i] = mkv8(lg[2 * i], lg[2 * i + 1]);
#pragma unroll
            for (int nt = 0; nt < 8; ++nt) {
                const _Float16* Bg = Whh16 + (size_t)(w * 128 + nt * 16 + l15) * 512 + kq * 8;
                v4f ag = {};
#pragma unroll
                for (int i = 0; i < 2; ++i)
                    ag = __builtin_amdgcn_mfma_f32_16x16x32_f16(
                        Ag[i], *(const v8h*)(Bg + (wave * 2 + i) * 32), ag, 0, 0, 0);
#pragma unroll
                for (int rr = 0; rr < 4; ++rr)
                    red[wave * 2048 + (kq * 4 + rr) * 128 + nt * 16 + l15] = ag[rr];
            }
            __syncthreads();
#pragma unroll
            for (int j = 0; j < 4; ++j) {
                const int o = tid + j * 512;           // row*128+col
                float gsum = 0.0f;
#pragma unroll
                for (int wv = 0; wv < 8; ++wv) gsum += red[wv * 2048 + o];
                ast32((uint32_t*)glin + (size_t)(g16 + (o >> 7)) * 2048 + w * 128 + (o & 127),
                      __builtin_bit_cast(uint32_t, gsum + bbv[j]));
            }
            publish_lines(fWBbase, 8, 16 * 32, (uint32_t)(t + 1));
        }
    } else {
        // ------------------ pair block ------------------
        const int p = bid - 192, b0 = 2 * p, r = p >> 3, pl = p & 7;
        uint32_t* fPbase = ctrs + (size_t)(r * 128 + pl) * 32;              // store stride 8*32
        const uint32_t* fWAbase = ctrs + FWA_OFF + (size_t)(r * 128 + pl * 16) * 32;  // poll 16
        const uint32_t* fWBbase = ctrs + FWB_OFF + (size_t)(r * 128 + pl * 16) * 32;
        _Float16* XeL = (_Float16*)arena;               // 128 KB
        float* sc = (float*)(arena + 131072);
        float* dstL = (float*)(arena + 131584);         // [2][512]
        float* cstL = (float*)(arena + 135680);
        float* ctxl = (float*)(arena + 139776);
        float* ytl = (float*)(arena + 143872);
        float* red0 = (float*)(arena + 143880);

        // one-time: Xe slice (2 batches) -> LDS f16
        {
            const float* xsrc = Xe + (size_t)b0 * 64 * 512;
#pragma unroll
            for (int i = 0; i < 16; ++i) {
                const int u = tid + i * 512;
                *(v8h*)(XeL + (size_t)u * 8) = cvt8(xsrc + (size_t)u * 8);
            }
        }
        for (int i = tid; i < 1024; i += 512) { dstL[i] = 0.0f; cstL[i] = 0.0f; }
        const float wih_i = Wih[tid], wih_f = Wih[512 + tid],
                    wih_g = Wih[1024 + tid], wih_o = Wih[1536 + tid];
        uint32_t* Abu = (uint32_t*)Ab;
        const uint32_t* partB = (const uint32_t*)partS;
        __syncthreads();

        for (int t = 0; t < 64; ++t) {
            wait_lines(fWAbase, 16, (uint32_t)(t + 1));
            {   // sum 16 worker partials per (b,t): 4 threads per combo
                const int cmb = tid >> 2, wq = tid & 3;
                const int blv = cmb >> 6, tt = cmb & 63;
                float acc = 0.0f;
#pragma unroll
                for (int i = 0; i < 4; ++i)
                    acc += __builtin_bit_cast(float,
                        ald32(partB + (((size_t)p * 16 + wq * 4 + i) * 2 + blv) * 64 + tt));
                acc += __shfl_xor(acc, 1, 64);
                acc += __shfl_xor(acc, 2, 64);
                if (wq == 0) sc[cmb] = acc;
            }
            __syncthreads();

            // ---- joint softmax over the pair's 128 scores ----
            if (tid < 64) {
                float m2 = fmaxf(sc[tid], sc[tid + 64]);
#pragma unroll
                for (int off = 32; off; off >>= 1) m2 = fmaxf(m2, __shfl_xor(m2, off, 64));
                float e0v = __expf(sc[tid] - m2);
                float e1v = __expf(sc[tid + 64] - m2);
                sc[tid] = e0v; sc[tid + 64] = e1v;
                float ssum = e0v + e1v;
#pragma unroll
                for (int off = 32; off; off >>= 1) ssum += __shfl_xor(ssum, off, 64);
                if (tid == 0) red0[0] = 1.0f / ssum;
            }
            __syncthreads();
            const float inv = red0[0];

            // ---- context from XeL (LDS) ----
            {
                const int blv = tid >> 8, m2 = (tid & 255) * 2;
                const _Float16* xb = XeL + (size_t)blv * 64 * 512 + m2;
                float a0 = 0.0f, a1 = 0.0f;
#pragma unroll 8
                for (int tt = 0; tt < 64; ++tt) {
                    const h2v xv = *(const h2v*)(xb + (size_t)tt * 512);
                    const float bta = sc[blv * 64 + tt];
                    a0 += bta * (float)xv[0];
                    a1 += bta * (float)xv[1];
                }
                ctxl[blv * 512 + m2] = a0 * inv;
                ctxl[blv * 512 + m2 + 1] = a1 * inv;
            }
            __syncthreads();

            // ---- wait glin; issue gate loads; ytilde in the shadow ----
            wait_lines(fWBbase, 16, (uint32_t)(t + 1));
            uint32_t gv[2][4];
#pragma unroll
            for (int blv = 0; blv < 2; ++blv) {
                const uint32_t* gb = (const uint32_t*)glin + (size_t)(b0 + blv) * 2048 + tid;
                gv[blv][0] = ald32(gb);
                gv[blv][1] = ald32(gb + 512);
                gv[blv][2] = ald32(gb + 1024);
                gv[blv][3] = ald32(gb + 1536);
            }
            if (tid < 128) {
                const int blv = tid >> 6, l2 = tid & 63;
                float acc = 0.0f;
#pragma unroll
                for (int j = 0; j < 8; ++j) acc += ctxl[blv * 512 + l2 * 8 + j] * Wfc[l2 * 8 + j];
#pragma unroll
                for (int off = 32; off; off >>= 1) acc += __shfl_xor(acc, off, 64);
                if (l2 == 0)
                    ytl[blv] = acc + Wfc[512] * ypr[(size_t)(b0 + blv) * 64 + t] + bfc[0];
            }
            __syncthreads();

            // ---- gates + LSTM update ----
#pragma unroll
            for (int blv = 0; blv < 2; ++blv) {
                const float yt = ytl[blv];
                float ii = __builtin_bit_cast(float, gv[blv][0]) + yt * wih_i;
                float ff = __builtin_bit_cast(float, gv[blv][1]) + yt * wih_f;
                float ggv = __builtin_bit_cast(float, gv[blv][2]) + yt * wih_g;
                float oo = __builtin_bit_cast(float, gv[blv][3]) + yt * wih_o;
                float cprev = cstL[blv * 512 + tid];
                float cn = fast_sigmoid(ff) * cprev + fast_sigmoid(ii) * fast_tanh(ggv);
                float dn = fast_sigmoid(oo) * fast_tanh(cn);
                cstL[blv * 512 + tid] = cn;
                dstL[blv * 512 + tid] = dn;
            }
            __syncthreads();
            // ---- publish Ab = [d|c] f16 ----
#pragma unroll
            for (int it = 0; it < 2; ++it) {
                const int idx = tid + it * 512;
                const int blv = idx >> 9, half = (idx >> 8) & 1, jj = idx & 255;
                const float x0 = half ? cstL[blv * 512 + jj * 2] : dstL[blv * 512 + jj * 2];
                const float x1 = half ? cstL[blv * 512 + jj * 2 + 1] : dstL[blv * 512 + jj * 2 + 1];
                ast32(Abu + (size_t)(b0 + blv) * 512 + half * 256 + jj, packh(x0, x1));
            }
            if (t == 63 && tid < 128) {
                const int blv = tid >> 6, l2 = tid & 63;
                float acc = 0.0f;
#pragma unroll
                for (int j = 0; j < 8; ++j) {
                    const int e = l2 * 8 + j;
                    acc += dstL[blv * 512 + e] * Wfin[e] + ctxl[blv * 512 + e] * Wfin[512 + e];
                }
#pragma unroll
                for (int off = 32; off; off >>= 1) acc += __shfl_xor(acc, off, 64);
                if (l2 == 0) out[b0 + blv] = acc + bfin[0];
            }
            publish_lines(fPbase, 16, 8 * 32, (uint32_t)(t + 1));
        }
    }
}

extern "C" void kernel_launch(void* const* d_in, const int* in_sizes, int n_in,
                              void* d_out, int out_size, void* d_ws, size_t ws_size,
                              hipStream_t stream)
{
    const float* Xe   = (const float*)d_in[0];
    const float* ypr  = (const float*)d_in[1];
    const float* Wa1  = (const float*)d_in[2];
    const float* ba1  = (const float*)d_in[3];
    const float* Wa2  = (const float*)d_in[4];
    const float* ba2  = (const float*)d_in[5];
    const float* Wih  = (const float*)d_in[6];
    const float* Whh  = (const float*)d_in[7];
    const float* bih  = (const float*)d_in[8];
    const float* bhh  = (const float*)d_in[9];
    const float* Wfc  = (const float*)d_in[10];
    const float* bfc  = (const float*)d_in[11];
    const float* Wfin = (const float*)d_in[12];
    const float* bfin = (const float*)d_in[13];
    float* out = (float*)d_out;

    char* w = (char*)d_ws;
    uint32_t* ctrs  = (uint32_t*)w;                 w += 393216;                       // 384 KB
    _Float16* Ab    = (_Float16*)w;                 w += (size_t)128 * 1024 * 2;       // 256 KB
    float*    glin  = (float*)w;                    w += (size_t)128 * 2048 * 4;       // 1 MB
    float*    partS = (float*)w;                    w += (size_t)64 * 16 * 2 * 64 * 4; // 512 KB
    _Float16* hx    = (_Float16*)w;                 w += (size_t)8192 * 512 * 2;       // 8 MB
    _Float16* Wa1a  = (_Float16*)w;                 w += (size_t)512 * 1024 * 2;       // 1 MB
    _Float16* Whh16 = (_Float16*)w;                 w += (size_t)2048 * 512 * 2;       // 2 MB

    void* args[] = {
        (void*)&Xe, (void*)&ypr, (void*)&Wa1, (void*)&ba1, (void*)&Wa2, (void*)&ba2,
        (void*)&Wih, (void*)&Whh, (void*)&bih, (void*)&bhh, (void*)&Wfc, (void*)&bfc,
        (void*)&Wfin, (void*)&bfin, (void*)&out,
        (void*)&ctrs, (void*)&Ab, (void*)&glin, (void*)&partS, (void*)&hx,
        (void*)&Wa1a, (void*)&Whh16
    };
    hipLaunchCooperativeKernel((const void*)fused_decoder, dim3(256), dim3(512),
                               args, 0, stream);
}